// Round 1
// baseline (786.368 us; speedup 1.0000x reference)
//
#include <hip/hip_runtime.h>
#include <hip/hip_bf16.h>

#define Nn 50000
#define Ee 800000
#define INF_ 128
#define HIDF 96
#define HH 8
#define DD 12
#define GG 64
#define OUTF 10

#define SCAN_CHUNK 512
#define SCAN_BLOCKS ((Nn + SCAN_CHUNK - 1) / SCAN_CHUNK)   // 98
#define NSB ((Nn + 255) / 256)                             // 196
#define RB 128   // readout partial blocks

// byte-packed LDS histogram CSR build
#define HCHK 256                // edge chunks (= blocks)
#define HCHKE (Ee / HCHK)       // 3125 edges per chunk
#define NW 12512                // packed words: 4 keys/word, 50048 >= Nn
#define DBIN 64                 // degree bins for counting sort

// ---------------- hist pass A: single-pass dual byte-packed LDS histograms ----------------
// 2 x 12512 words = 100 KB LDS; grid = 256 blocks = 1/CU either way.
__global__ __launch_bounds__(512) void hist_lds(const int* __restrict__ src,
                                                const int* __restrict__ dst,
                                                unsigned int* __restrict__ partS,
                                                unsigned int* __restrict__ partD,
                                                unsigned char* __restrict__ edge_slot) {
    __shared__ unsigned int hS[NW];
    __shared__ unsigned int hD[NW];
    int b = blockIdx.x, t = threadIdx.x;
    for (int i = t; i < NW; i += 512) { hS[i] = 0u; hD[i] = 0u; }
    __syncthreads();
    int base = b * HCHKE;
    for (int i = t; i < HCHKE; i += 512) {
        int d = dst[base + i];
        unsigned int old = atomicAdd(&hD[d >> 2], 1u << ((d & 3) * 8));
        edge_slot[base + i] = (unsigned char)((old >> ((d & 3) * 8)) & 0xFFu);
        int s = src[base + i];
        atomicAdd(&hS[s >> 2], 1u << ((s & 3) * 8));
    }
    __syncthreads();
    for (int i = t; i < NW; i += 512) {
        partD[(size_t)b * NW + i] = hD[i];
        partS[(size_t)b * NW + i] = hS[i];
    }
}

// ---------------- hist pass B: packed chunk-prefix on partD; cnt_in, degs, degree-bin hist ----------------
__global__ __launch_bounds__(256) void hist_scan(unsigned int* __restrict__ partD,
                                                 const unsigned int* __restrict__ partS,
                                                 int* __restrict__ cnt_in,
                                                 float* __restrict__ degI_is,
                                                 float* __restrict__ degO_is,
                                                 int* __restrict__ dcnt) {
    __shared__ int hbin[DBIN];
    int t = threadIdx.x;
    if (t < DBIN) hbin[t] = 0;
    __syncthreads();
    int w = blockIdx.x * 256 + t;
    if (w < NW) {
        unsigned int run = 0u, totS = 0u;
        for (int b = 0; b < HCHK; ++b) {
            size_t idx = (size_t)b * NW + w;
            unsigned int v = partD[idx];
            partD[idx] = run;               // exclusive prefix across chunks (packed bytes)
            run += v;
            totS += partS[idx];
        }
#pragma unroll
        for (int j = 0; j < 4; ++j) {
            int k = w * 4 + j;
            if (k < Nn) {
                int di = (int)((run >> (j * 8)) & 0xFFu);
                int dо = (int)((totS >> (j * 8)) & 0xFFu);
                cnt_in[k] = di;
                degI_is[k] = rsqrtf((float)max(di, 1));
                degO_is[k] = rsqrtf((float)max(dо, 1));
                atomicAdd(&hbin[DBIN - 1 - min(di, DBIN - 1)], 1);
            }
        }
    }
    __syncthreads();
    if (t < DBIN && hbin[t]) atomicAdd(&dcnt[t], hbin[t]);
}

// ---------------- hierarchical scan, stage 1 ----------------
__global__ __launch_bounds__(256) void scan1_kernel(const int* __restrict__ cnt,
                                                    int* __restrict__ row_start,
                                                    int* __restrict__ blk_sum, int N) {
    __shared__ int part[256];
    int t = threadIdx.x;
    int base = blockIdx.x * SCAN_CHUNK;
    int i0 = base + 2 * t, i1 = i0 + 1;
    int a = (i0 < N) ? cnt[i0] : 0;
    int b = (i1 < N) ? cnt[i1] : 0;
    int s = a + b;
    part[t] = s;
    __syncthreads();
    for (int off = 1; off < 256; off <<= 1) {
        int v = (t >= off) ? part[t - off] : 0;
        __syncthreads();
        part[t] += v;
        __syncthreads();
    }
    int excl = part[t] - s;
    if (i0 < N) row_start[i0] = excl;
    if (i1 < N) row_start[i1] = excl + a;
    if (t == 255) blk_sum[blockIdx.x] = part[255];
}

// ---------------- stage 2 (block 0) + degree-bin scan (block 1) ----------------
__global__ __launch_bounds__(128) void scan2_kernel(const int* __restrict__ blk_sum,
                                                    int* __restrict__ blk_off,
                                                    int* __restrict__ row_start,
                                                    const int* __restrict__ dcnt,
                                                    int* __restrict__ dcur, int N) {
    __shared__ int part[128];
    int t = threadIdx.x;
    if (blockIdx.x == 0) {
        int v0 = (t < SCAN_BLOCKS) ? blk_sum[t] : 0;
        part[t] = v0;
        __syncthreads();
        for (int off = 1; off < 128; off <<= 1) {
            int v = (t >= off) ? part[t - off] : 0;
            __syncthreads();
            part[t] += v;
            __syncthreads();
        }
        blk_off[t] = part[t] - v0;
        if (t == 127) row_start[N] = part[127];
    } else {
        int v0 = (t < DBIN) ? dcnt[t] : 0;
        part[t] = v0;
        __syncthreads();
        for (int off = 1; off < DBIN; off <<= 1) {
            int v = (t >= off) ? part[t - off] : 0;
            __syncthreads();
            part[t] += v;
            __syncthreads();
        }
        if (t < DBIN) dcur[t] = part[t] - v0;   // exclusive
    }
}

// ---------------- stage 3 (blocks 0..SCAN_BLOCKS-1) + perm scatter (rest) ----------------
__global__ __launch_bounds__(256) void scan3_kernel(int* __restrict__ row_start,
                                                    const int* __restrict__ blk_off,
                                                    const int* __restrict__ cnt_in,
                                                    int* __restrict__ dcur,
                                                    int* __restrict__ perm, int N) {
    int t = threadIdx.x;
    if (blockIdx.x < SCAN_BLOCKS) {
        int base = blockIdx.x * SCAN_CHUNK;
        int off = blk_off[blockIdx.x];
        int i0 = base + 2 * t, i1 = i0 + 1;
        if (i0 < N) row_start[i0] += off;
        if (i1 < N) row_start[i1] += off;
    } else {
        __shared__ int lh[DBIN];
        __shared__ int lbase[DBIN];
        if (t < DBIN) lh[t] = 0;
        __syncthreads();
        int n = (blockIdx.x - SCAN_BLOCKS) * 256 + t;
        int bin = 0, lslot = 0;
        if (n < N) {
            bin = DBIN - 1 - min(cnt_in[n], DBIN - 1);
            lslot = atomicAdd(&lh[bin], 1);
        }
        __syncthreads();
        if (t < DBIN) lbase[t] = lh[t] ? atomicAdd(&dcur[t], lh[t]) : 0;
        __syncthreads();
        if (n < N) perm[lbase[bin] + lslot] = n;
    }
}

// ---------------- CSR fill: atomic-free ----------------
__global__ __launch_bounds__(512) void fill_kernel(const int* __restrict__ src,
                                                   const int* __restrict__ dst,
                                                   const int* __restrict__ row_start,
                                                   const unsigned int* __restrict__ partD,
                                                   const unsigned char* __restrict__ edge_slot,
                                                   int* __restrict__ csr_src) {
    int b = blockIdx.x, t = threadIdx.x;
    int base = b * HCHKE;
    size_t po = (size_t)b * NW;
    for (int i = t; i < HCHKE; i += 512) {
        int e = base + i;
        int d = dst[e];
        int cb = (int)((partD[po + (d >> 2)] >> ((d & 3) * 8)) & 0xFFu);
        csr_src[row_start[d] + cb + (int)edge_slot[e]] = src[e];
    }
}

// ---------------- staged-LDS GEMM, register-prefetch pipelined ----------------
// out[N x 96] = diag(rowScale) * A[N x K] @ W[K x 96] (+bias)
// Pipeline: issue next chunk's global loads into registers BEFORE the compute
// phase; vmcnt drain + LDS write happen after the post-compute barrier, so
// global latency hides under the ~4K-cycle FMA phase (T14 async-STAGE split).
__global__ __launch_bounds__(192, 3) void gemm96(const float* __restrict__ A, int K,
                                                 const float* __restrict__ W,
                                                 const float* __restrict__ bias,
                                                 const float* __restrict__ rowScale,
                                                 float* __restrict__ out, int N) {
    __shared__ float A_lds[64 * 36];
    __shared__ float W_lds[32 * 96];
    const int t = threadIdx.x;
    const int row0 = blockIdx.x * 64;
    const int tcol = t % 24;
    const int trow = t / 24;
    float acc[8][4];
#pragma unroll
    for (int i = 0; i < 8; ++i)
#pragma unroll
        for (int j = 0; j < 4; ++j) acc[i][j] = 0.f;

    float4 wreg[4];
    float4 areg[3];
    float  sreg[3];

    auto loadWA = [&](int k0) {
#pragma unroll
        for (int u = 0; u < 4; ++u)
            wreg[u] = ((const float4*)W)[(size_t)k0 * 24 + t + u * 192];
#pragma unroll
        for (int u = 0; u < 3; ++u) {
            int i = t + u * 192;
            if (i < 512) {
                int r = i >> 3, kk = i & 7;
                int gr = row0 + r;
                gr = gr < N ? gr : N - 1;   // clamp: garbage rows never stored
                areg[u] = *((const float4*)(A + (size_t)gr * K + k0 + kk * 4));
                sreg[u] = rowScale ? rowScale[gr] : 1.f;
            }
        }
    };
    auto storeLDS = [&]() {
#pragma unroll
        for (int u = 0; u < 4; ++u)
            ((float4*)W_lds)[t + u * 192] = wreg[u];
#pragma unroll
        for (int u = 0; u < 3; ++u) {
            int i = t + u * 192;
            if (i < 512) {
                int r = i >> 3, kk = i & 7;
                float4 v = areg[u];
                float s = sreg[u];
                v.x *= s; v.y *= s; v.z *= s; v.w *= s;
                *((float4*)(A_lds + r * 36 + kk * 4)) = v;
            }
        }
    };

    loadWA(0);
    storeLDS();
    __syncthreads();
    for (int k0 = 0;;) {
        int kn = k0 + 32;
        bool more = kn < K;
        if (more) loadWA(kn);   // issue early; consumed after next barrier
#pragma unroll
        for (int kk4 = 0; kk4 < 8; ++kk4) {
            float4 a[8];
#pragma unroll
            for (int i = 0; i < 8; ++i)
                a[i] = *((const float4*)(A_lds + (trow + 8 * i) * 36 + kk4 * 4));
#pragma unroll
            for (int kk = 0; kk < 4; ++kk) {
                float4 wv = *((const float4*)(W_lds + (kk4 * 4 + kk) * 96 + tcol * 4));
#pragma unroll
                for (int i = 0; i < 8; ++i) {
                    float av = (kk == 0) ? a[i].x : (kk == 1) ? a[i].y : (kk == 2) ? a[i].z : a[i].w;
                    acc[i][0] = fmaf(av, wv.x, acc[i][0]);
                    acc[i][1] = fmaf(av, wv.y, acc[i][1]);
                    acc[i][2] = fmaf(av, wv.z, acc[i][2]);
                    acc[i][3] = fmaf(av, wv.w, acc[i][3]);
                }
            }
        }
        if (!more) break;
        __syncthreads();
        storeLDS();
        __syncthreads();
        k0 = kn;
    }
    float4 b4 = bias ? *((const float4*)(bias + tcol * 4)) : make_float4(0.f, 0.f, 0.f, 0.f);
#pragma unroll
    for (int i = 0; i < 8; ++i) {
        int gr = row0 + trow + 8 * i;
        if (gr < N) {
            float4 o = make_float4(acc[i][0] + b4.x, acc[i][1] + b4.y,
                                   acc[i][2] + b4.z, acc[i][3] + b4.w);
            *((float4*)(out + (size_t)gr * 96 + tcol * 4)) = o;
        }
    }
}

// ---------------- dual GEMM, register-prefetch pipelined (K=96) ----------------
__global__ __launch_bounds__(192, 3) void gemm96x2(const float* __restrict__ A,
                                                   const float* __restrict__ W1_, const float* __restrict__ b1_,
                                                   const float* __restrict__ W2_, const float* __restrict__ b2_,
                                                   float* __restrict__ out1, float* __restrict__ out2, int N) {
    __shared__ float A_lds[64 * 36];
    __shared__ float W_lds[2 * 32 * 96];
    const int t = threadIdx.x;
    const int row0 = blockIdx.x * 64;
    const int tcol = t % 24;
    const int trow = t / 24;
    float acc1[8][4], acc2[8][4];
#pragma unroll
    for (int i = 0; i < 8; ++i)
#pragma unroll
        for (int j = 0; j < 4; ++j) { acc1[i][j] = 0.f; acc2[i][j] = 0.f; }

    float4 wreg1[4], wreg2[4];
    float4 areg[3];

    auto loadWA = [&](int k0) {
#pragma unroll
        for (int u = 0; u < 4; ++u) {
            wreg1[u] = ((const float4*)W1_)[(size_t)k0 * 24 + t + u * 192];
            wreg2[u] = ((const float4*)W2_)[(size_t)k0 * 24 + t + u * 192];
        }
#pragma unroll
        for (int u = 0; u < 3; ++u) {
            int i = t + u * 192;
            if (i < 512) {
                int r = i >> 3, kk = i & 7;
                int gr = row0 + r;
                gr = gr < N ? gr : N - 1;   // clamp: garbage rows never stored
                areg[u] = *((const float4*)(A + (size_t)gr * 96 + k0 + kk * 4));
            }
        }
    };
    auto storeLDS = [&]() {
#pragma unroll
        for (int u = 0; u < 4; ++u) {
            ((float4*)W_lds)[t + u * 192] = wreg1[u];
            ((float4*)(W_lds + 32 * 96))[t + u * 192] = wreg2[u];
        }
#pragma unroll
        for (int u = 0; u < 3; ++u) {
            int i = t + u * 192;
            if (i < 512) {
                int r = i >> 3, kk = i & 7;
                *((float4*)(A_lds + r * 36 + kk * 4)) = areg[u];
            }
        }
    };

    loadWA(0);
    storeLDS();
    __syncthreads();
    for (int k0 = 0;;) {
        int kn = k0 + 32;
        bool more = kn < 96;
        if (more) loadWA(kn);   // issue early; consumed after next barrier
#pragma unroll
        for (int kk4 = 0; kk4 < 8; ++kk4) {
            float4 a[8];
#pragma unroll
            for (int i = 0; i < 8; ++i)
                a[i] = *((const float4*)(A_lds + (trow + 8 * i) * 36 + kk4 * 4));
#pragma unroll
            for (int kk = 0; kk < 4; ++kk) {
                float4 wv1 = *((const float4*)(W_lds + (kk4 * 4 + kk) * 96 + tcol * 4));
                float4 wv2 = *((const float4*)(W_lds + 32 * 96 + (kk4 * 4 + kk) * 96 + tcol * 4));
#pragma unroll
                for (int i = 0; i < 8; ++i) {
                    float av = (kk == 0) ? a[i].x : (kk == 1) ? a[i].y : (kk == 2) ? a[i].z : a[i].w;
                    acc1[i][0] = fmaf(av, wv1.x, acc1[i][0]);
                    acc1[i][1] = fmaf(av, wv1.y, acc1[i][1]);
                    acc1[i][2] = fmaf(av, wv1.z, acc1[i][2]);
                    acc1[i][3] = fmaf(av, wv1.w, acc1[i][3]);
                    acc2[i][0] = fmaf(av, wv2.x, acc2[i][0]);
                    acc2[i][1] = fmaf(av, wv2.y, acc2[i][1]);
                    acc2[i][2] = fmaf(av, wv2.z, acc2[i][2]);
                    acc2[i][3] = fmaf(av, wv2.w, acc2[i][3]);
                }
            }
        }
        if (!more) break;
        __syncthreads();
        storeLDS();
        __syncthreads();
        k0 = kn;
    }
    float4 bb1 = *((const float4*)(b1_ + tcol * 4));
    float4 bb2 = *((const float4*)(b2_ + tcol * 4));
#pragma unroll
    for (int i = 0; i < 8; ++i) {
        int gr = row0 + trow + 8 * i;
        if (gr < N) {
            float4 o1 = make_float4(acc1[i][0] + bb1.x, acc1[i][1] + bb1.y,
                                    acc1[i][2] + bb1.z, acc1[i][3] + bb1.w);
            float4 o2 = make_float4(acc2[i][0] + bb2.x, acc2[i][1] + bb2.y,
                                    acc2[i][2] + bb2.z, acc2[i][3] + bb2.w);
            *((float4*)(out1 + (size_t)gr * 96 + tcol * 4)) = o1;
            *((float4*)(out2 + (size_t)gr * 96 + tcol * 4)) = o2;
        }
    }
}

// ---------------- GraphConv aggregate (degree-sorted via perm) ----------------
__global__ __launch_bounds__(192) void gc_agg(const float* __restrict__ hW,
                                              const int* __restrict__ row_start,
                                              const int* __restrict__ csr_src,
                                              const float* __restrict__ degI_is,
                                              const float* __restrict__ bias,
                                              const int* __restrict__ perm,
                                              float* __restrict__ hout, int N) {
    int tid = blockIdx.x * 192 + threadIdx.x;
    int p = tid / 24;
    int c = (tid % 24) * 4;
    if (p >= N) return;
    int n = perm[p];
    int beg = row_start[n], end = row_start[n + 1];
    float4 s = make_float4(0.f, 0.f, 0.f, 0.f);
    int e = beg;
    for (; e + 4 <= end; e += 4) {
        int i0 = csr_src[e], i1 = csr_src[e + 1], i2 = csr_src[e + 2], i3 = csr_src[e + 3];
        float4 v0 = *(const float4*)(hW + (size_t)i0 * 96 + c);
        float4 v1 = *(const float4*)(hW + (size_t)i1 * 96 + c);
        float4 v2 = *(const float4*)(hW + (size_t)i2 * 96 + c);
        float4 v3 = *(const float4*)(hW + (size_t)i3 * 96 + c);
        s.x += (v0.x + v1.x) + (v2.x + v3.x);
        s.y += (v0.y + v1.y) + (v2.y + v3.y);
        s.z += (v0.z + v1.z) + (v2.z + v3.z);
        s.w += (v0.w + v1.w) + (v2.w + v3.w);
    }
    for (; e < end; ++e) {
        int i0 = csr_src[e];
        float4 v0 = *(const float4*)(hW + (size_t)i0 * 96 + c);
        s.x += v0.x; s.y += v0.y; s.z += v0.z; s.w += v0.w;
    }
    float dn = degI_is[n];
    float4 b = *(const float4*)(bias + c);
    float4 o;
    o.x = fmaxf(fmaf(s.x, dn, b.x), 0.f);
    o.y = fmaxf(fmaf(s.y, dn, b.y), 0.f);
    o.z = fmaxf(fmaf(s.z, dn, b.z), 0.f);
    o.w = fmaxf(fmaf(s.w, dn, b.w), 0.f);
    *(float4*)(hout + (size_t)n * 96 + c) = o;
}

// ---------------- GATv2: dual independent online-softmax chains, merged at end ----------------
__global__ __launch_bounds__(256) void gat_agg(const float* __restrict__ fs,
                                               const float* __restrict__ fd,
                                               const float* __restrict__ attn,
                                               const int* __restrict__ row_start,
                                               const int* __restrict__ csr_src,
                                               const int* __restrict__ perm,
                                               float* __restrict__ hout, int N) {
    int tid = blockIdx.x * 256 + threadIdx.x;
    int p = tid >> 3, hd = tid & 7;
    if (p >= N) return;
    int n = perm[p];
    float att[12], fdv[12];
    {
        const float4* ap = (const float4*)(attn + hd * 12);
        float4 a0 = ap[0], a1 = ap[1], a2 = ap[2];
        att[0]=a0.x; att[1]=a0.y; att[2]=a0.z; att[3]=a0.w;
        att[4]=a1.x; att[5]=a1.y; att[6]=a1.z; att[7]=a1.w;
        att[8]=a2.x; att[9]=a2.y; att[10]=a2.z; att[11]=a2.w;
        const float4* dp = (const float4*)(fd + (size_t)n * 96 + hd * 12);
        float4 d0 = dp[0], d1 = dp[1], d2 = dp[2];
        fdv[0]=d0.x; fdv[1]=d0.y; fdv[2]=d0.z; fdv[3]=d0.w;
        fdv[4]=d1.x; fdv[5]=d1.y; fdv[6]=d1.z; fdv[7]=d1.w;
        fdv[8]=d2.x; fdv[9]=d2.y; fdv[10]=d2.z; fdv[11]=d2.w;
    }
    int beg = row_start[n], end = row_start[n + 1];
    float m0 = -3.0e38f, den0 = 0.f, m1 = -3.0e38f, den1 = 0.f;
    float A0[12], A1[12];
#pragma unroll
    for (int d = 0; d < 12; ++d) { A0[d] = 0.f; A1[d] = 0.f; }

    auto proc = [&](const float4& s0, const float4& s1, const float4& s2,
                    float& m, float& den, float* acc) {
        float fsv[12];
        fsv[0]=s0.x; fsv[1]=s0.y; fsv[2]=s0.z; fsv[3]=s0.w;
        fsv[4]=s1.x; fsv[5]=s1.y; fsv[6]=s1.z; fsv[7]=s1.w;
        fsv[8]=s2.x; fsv[9]=s2.y; fsv[10]=s2.z; fsv[11]=s2.w;
        float logit = 0.f;
#pragma unroll
        for (int d = 0; d < 12; ++d) {
            float u = fsv[d] + fdv[d];
            u = u > 0.f ? u : 0.2f * u;
            logit = fmaf(u, att[d], logit);
        }
        float nm = fmaxf(m, logit);
        float cc = __expf(m - nm);
        float w  = __expf(logit - nm);
        den = fmaf(den, cc, w);
#pragma unroll
        for (int d = 0; d < 12; ++d) acc[d] = fmaf(acc[d], cc, w * fsv[d]);
        m = nm;
    };

    int e = beg;
    for (; e + 4 <= end; e += 4) {
        int i0 = csr_src[e], i1 = csr_src[e + 1], i2 = csr_src[e + 2], i3 = csr_src[e + 3];
        const float4* p0 = (const float4*)(fs + (size_t)i0 * 96 + hd * 12);
        const float4* p1 = (const float4*)(fs + (size_t)i1 * 96 + hd * 12);
        const float4* p2 = (const float4*)(fs + (size_t)i2 * 96 + hd * 12);
        const float4* p3 = (const float4*)(fs + (size_t)i3 * 96 + hd * 12);
        float4 a0 = p0[0], a1 = p0[1], a2 = p0[2];
        float4 b0 = p1[0], b1 = p1[1], b2 = p1[2];
        float4 c0 = p2[0], c1 = p2[1], c2 = p2[2];
        float4 d0 = p3[0], d1 = p3[1], d2 = p3[2];
        proc(a0, a1, a2, m0, den0, A0);
        proc(b0, b1, b2, m1, den1, A1);
        proc(c0, c1, c2, m0, den0, A0);
        proc(d0, d1, d2, m1, den1, A1);
    }
    for (; e < end; ++e) {
        int i0 = csr_src[e];
        const float4* p0 = (const float4*)(fs + (size_t)i0 * 96 + hd * 12);
        float4 a0 = p0[0], a1 = p0[1], a2 = p0[2];
        proc(a0, a1, a2, m0, den0, A0);
    }
    // merge the two chains
    float nm = fmaxf(m0, m1);
    float c0 = __expf(m0 - nm), c1 = __expf(m1 - nm);
    float den = den0 * c0 + den1 * c1;
    float inv = den > 0.f ? 1.f / den : 0.f;
    float* op = hout + (size_t)n * 96 + hd * 12;
#pragma unroll
    for (int d = 0; d < 12; ++d)
        op[d] = fmaxf((A0[d] * c0 + A1[d] * c1) * inv, 0.f);
}

// ---------------- per-graph max readout: stage 1, per-block LDS max -> partials ----------------
__global__ __launch_bounds__(384) void readout_partial(const float* __restrict__ h,
                                                       const int* __restrict__ graph_id,
                                                       float* __restrict__ partial, int N) {
    __shared__ int lhg[GG * 96];
    int t = threadIdx.x;
    for (int i = t; i < GG * 96; i += 384) lhg[i] = 0;
    __syncthreads();
    int f = t % 96, nl = t / 96;
    for (int n0 = blockIdx.x * 4; n0 < N; n0 += RB * 4) {
        int n = n0 + nl;
        if (n < N) {
            int g = graph_id[n];
            float v = h[(size_t)n * 96 + f];
            atomicMax(&lhg[g * 96 + f], __float_as_int(v));
        }
    }
    __syncthreads();
    for (int i = t; i < GG * 96; i += 384)
        partial[(size_t)blockIdx.x * (GG * 96) + i] = __int_as_float(lhg[i]);
}

// ---------------- readout stage 2: reduce partials ----------------
__global__ void readout_reduce(const float* __restrict__ partial, float* __restrict__ hg) {
    int i = blockIdx.x * 256 + threadIdx.x;
    if (i < GG * 96) {
        float m = 0.f;
        for (int b = 0; b < RB; ++b) m = fmaxf(m, partial[(size_t)b * (GG * 96) + i]);
        hg[i] = m;
    }
}

// ---------------- classifier MLP: one block per graph ----------------
__global__ __launch_bounds__(96) void mlp_kernel(const float* __restrict__ hg,
                                                 const float* __restrict__ Wc1, const float* __restrict__ bc1,
                                                 const float* __restrict__ Wc2, const float* __restrict__ bc2,
                                                 const float* __restrict__ Wc3, const float* __restrict__ bc3,
                                                 float* __restrict__ out) {
    int g = blockIdx.x;
    int t = threadIdx.x;
    __shared__ float z0[96], z1[96], z2[48];
    z0[t] = hg[(size_t)g * 96 + t];
    __syncthreads();
    float s = bc1[t];
    for (int k = 0; k < 96; ++k) s = fmaf(z0[k], Wc1[k * 96 + t], s);
    z1[t] = fmaxf(s, 0.f);
    __syncthreads();
    if (t < 48) {
        float s2 = bc2[t];
        for (int k = 0; k < 96; ++k) s2 = fmaf(z1[k], Wc2[k * 48 + t], s2);
        z2[t] = fmaxf(s2, 0.f);
    }
    __syncthreads();
    if (t < 10) {
        float s3 = bc3[t];
        for (int k = 0; k < 48; ++k) s3 = fmaf(z2[k], Wc3[k * 10 + t], s3);
        out[(size_t)g * 10 + t] = s3;
    }
}

extern "C" void kernel_launch(void* const* d_in, const int* in_sizes, int n_in,
                              void* d_out, int out_size, void* d_ws, size_t ws_size,
                              hipStream_t stream) {
    const float* x        = (const float*)d_in[0];
    const int*   src      = (const int*)d_in[1];
    const int*   dst      = (const int*)d_in[2];
    const int*   graph_id = (const int*)d_in[3];
    const float* W1  = (const float*)d_in[4];
    const float* b1  = (const float*)d_in[5];
    const float* W2  = (const float*)d_in[6];
    const float* b2  = (const float*)d_in[7];
    const float* Ws  = (const float*)d_in[8];
    const float* bs  = (const float*)d_in[9];
    const float* Wd  = (const float*)d_in[10];
    const float* bd  = (const float*)d_in[11];
    const float* attn = (const float*)d_in[12];
    const float* Wc1 = (const float*)d_in[13];
    const float* bc1 = (const float*)d_in[14];
    const float* Wc2 = (const float*)d_in[15];
    const float* bc2 = (const float*)d_in[16];
    const float* Wc3 = (const float*)d_in[17];
    const float* bc3 = (const float*)d_in[18];
    float* out = (float*)d_out;

    char* ws = (char*)d_ws;
    size_t off = 0;
    auto alloc = [&](size_t bytes) {
        char* p = ws + off;
        off = (off + bytes + 255) & ~(size_t)255;
        return p;
    };
    int*   cnt_in    = (int*)alloc(Nn * 4);
    int*   row_start = (int*)alloc((Nn + 1) * 4);
    unsigned char* edge_slot = (unsigned char*)alloc(Ee);
    int*   csr_src   = (int*)alloc(Ee * 4);
    int*   perm      = (int*)alloc(Nn * 4);
    float* degI_is   = (float*)alloc(Nn * 4);
    float* degO_is   = (float*)alloc(Nn * 4);
    float* bufH      = (float*)alloc((size_t)Nn * 96 * 4);
    float* bufT      = (float*)alloc((size_t)Nn * 96 * 4);
    float* bufFd     = (float*)alloc((size_t)Nn * 96 * 4);
    float* hg        = (float*)alloc(GG * 96 * 4);
    float* partial   = (float*)alloc((size_t)RB * GG * 96 * 4);
    int*   blk_sum   = (int*)alloc(128 * 4);
    int*   blk_off   = (int*)alloc(128 * 4);
    int*   dcnt      = (int*)alloc(DBIN * 4);
    int*   dcur      = (int*)alloc(DBIN * 4);

    // packed histogram partials alias the (not-yet-used) feature buffers:
    // HCHK*NW*4 = 12.8 MB each; bufT/bufFd are 19.2 MB each.
    unsigned int* partS = (unsigned int*)bufT;
    unsigned int* partD = (unsigned int*)bufFd;

    hipMemsetAsync(dcnt, 0, DBIN * 4, stream);

    // ---- CSR build + degrees + degree-sort (no global fp atomics, 6 kernels) ----
    hist_lds<<<HCHK, 512, 0, stream>>>(src, dst, partS, partD, edge_slot);
    hist_scan<<<(NW + 255) / 256, 256, 0, stream>>>(partD, partS, cnt_in, degI_is, degO_is, dcnt);
    scan1_kernel<<<SCAN_BLOCKS, 256, 0, stream>>>(cnt_in, row_start, blk_sum, Nn);
    scan2_kernel<<<2, 128, 0, stream>>>(blk_sum, blk_off, row_start, dcnt, dcur, Nn);
    scan3_kernel<<<SCAN_BLOCKS + NSB, 256, 0, stream>>>(row_start, blk_off, cnt_in, dcur, perm, Nn);
    fill_kernel<<<HCHK, 512, 0, stream>>>(src, dst, row_start, partD, edge_slot, csr_src);

    int gemm_blocks = (Nn + 63) / 64;
    int agg_blocks  = (Nn * 24 + 191) / 192;
    int gat_blocks  = (Nn * 8 + 255) / 256;

    // GraphConv 1: x[N,128] -> bufH
    gemm96<<<gemm_blocks, 192, 0, stream>>>(x, 128, W1, nullptr, degO_is, bufT, Nn);
    gc_agg<<<agg_blocks, 192, 0, stream>>>(bufT, row_start, csr_src, degI_is, b1, perm, bufH, Nn);
    // GraphConv 2
    gemm96<<<gemm_blocks, 192, 0, stream>>>(bufH, 96, W2, nullptr, degO_is, bufT, Nn);
    gc_agg<<<agg_blocks, 192, 0, stream>>>(bufT, row_start, csr_src, degI_is, b2, perm, bufH, Nn);

    // 3x GATv2: fused dual GEMM (fs,fd) then fused attention+aggregate
    for (int l = 0; l < 3; ++l) {
        const float* Wsl = Ws + (size_t)l * 96 * 96;
        const float* bsl = bs + (size_t)l * 96;
        const float* Wdl = Wd + (size_t)l * 96 * 96;
        const float* bdl = bd + (size_t)l * 96;
        const float* atl = attn + (size_t)l * 96;
        gemm96x2<<<gemm_blocks, 192, 0, stream>>>(bufH, Wsl, bsl, Wdl, bdl, bufT, bufFd, Nn);
        gat_agg<<<gat_blocks, 256, 0, stream>>>(bufT, bufFd, atl, row_start, csr_src, perm, bufH, Nn);
    }

    readout_partial<<<RB, 384, 0, stream>>>(bufH, graph_id, partial, Nn);
    readout_reduce<<<(GG * 96 + 255) / 256, 256, 0, stream>>>(partial, hg);
    mlp_kernel<<<GG, 96, 0, stream>>>(hg, Wc1, bc1, Wc2, bc2, Wc3, bc3, out);
}

// Round 2
// 687.724 us; speedup vs baseline: 1.1434x; 1.1434x over previous
//
#include <hip/hip_runtime.h>
#include <hip/hip_bf16.h>

#define Nn 50000
#define Ee 800000
#define INF_ 128
#define HIDF 96
#define HH 8
#define DD 12
#define GG 64
#define OUTF 10

#define SCAN_CHUNK 512
#define SCAN_BLOCKS ((Nn + SCAN_CHUNK - 1) / SCAN_CHUNK)   // 98
#define NSB ((Nn + 255) / 256)                             // 196
#define RB 128   // readout partial blocks

// byte-packed LDS histogram CSR build
#define HCHK 256                // edge chunks (= blocks)
#define HCHKE (Ee / HCHK)       // 3125 edges per chunk
#define NW 12512                // packed words: 4 keys/word, 50048 >= Nn
#define DBIN 64                 // degree bins for counting sort

// ---------------- hist pass A: single-pass dual byte-packed LDS histograms ----------------
// 2 x 12512 words = 100 KB LDS; grid = 256 blocks = 1/CU either way.
__global__ __launch_bounds__(512) void hist_lds(const int* __restrict__ src,
                                                const int* __restrict__ dst,
                                                unsigned int* __restrict__ partS,
                                                unsigned int* __restrict__ partD,
                                                unsigned char* __restrict__ edge_slot) {
    __shared__ unsigned int hS[NW];
    __shared__ unsigned int hD[NW];
    int b = blockIdx.x, t = threadIdx.x;
    for (int i = t; i < NW; i += 512) { hS[i] = 0u; hD[i] = 0u; }
    __syncthreads();
    int base = b * HCHKE;
    for (int i = t; i < HCHKE; i += 512) {
        int d = dst[base + i];
        unsigned int old = atomicAdd(&hD[d >> 2], 1u << ((d & 3) * 8));
        edge_slot[base + i] = (unsigned char)((old >> ((d & 3) * 8)) & 0xFFu);
        int s = src[base + i];
        atomicAdd(&hS[s >> 2], 1u << ((s & 3) * 8));
    }
    __syncthreads();
    for (int i = t; i < NW; i += 512) {
        partD[(size_t)b * NW + i] = hD[i];
        partS[(size_t)b * NW + i] = hS[i];
    }
}

// ---------------- hist pass B: packed chunk-prefix on partD; cnt_in, degs, degree-bin hist ----------------
__global__ __launch_bounds__(256) void hist_scan(unsigned int* __restrict__ partD,
                                                 const unsigned int* __restrict__ partS,
                                                 int* __restrict__ cnt_in,
                                                 float* __restrict__ degI_is,
                                                 float* __restrict__ degO_is,
                                                 int* __restrict__ dcnt) {
    __shared__ int hbin[DBIN];
    int t = threadIdx.x;
    if (t < DBIN) hbin[t] = 0;
    __syncthreads();
    int w = blockIdx.x * 256 + t;
    if (w < NW) {
        unsigned int run = 0u, totS = 0u;
        for (int b = 0; b < HCHK; ++b) {
            size_t idx = (size_t)b * NW + w;
            unsigned int v = partD[idx];
            partD[idx] = run;               // exclusive prefix across chunks (packed bytes)
            run += v;
            totS += partS[idx];
        }
#pragma unroll
        for (int j = 0; j < 4; ++j) {
            int k = w * 4 + j;
            if (k < Nn) {
                int di = (int)((run >> (j * 8)) & 0xFFu);
                int dо = (int)((totS >> (j * 8)) & 0xFFu);
                cnt_in[k] = di;
                degI_is[k] = rsqrtf((float)max(di, 1));
                degO_is[k] = rsqrtf((float)max(dо, 1));
                atomicAdd(&hbin[DBIN - 1 - min(di, DBIN - 1)], 1);
            }
        }
    }
    __syncthreads();
    if (t < DBIN && hbin[t]) atomicAdd(&dcnt[t], hbin[t]);
}

// ---------------- hierarchical scan, stage 1 ----------------
__global__ __launch_bounds__(256) void scan1_kernel(const int* __restrict__ cnt,
                                                    int* __restrict__ row_start,
                                                    int* __restrict__ blk_sum, int N) {
    __shared__ int part[256];
    int t = threadIdx.x;
    int base = blockIdx.x * SCAN_CHUNK;
    int i0 = base + 2 * t, i1 = i0 + 1;
    int a = (i0 < N) ? cnt[i0] : 0;
    int b = (i1 < N) ? cnt[i1] : 0;
    int s = a + b;
    part[t] = s;
    __syncthreads();
    for (int off = 1; off < 256; off <<= 1) {
        int v = (t >= off) ? part[t - off] : 0;
        __syncthreads();
        part[t] += v;
        __syncthreads();
    }
    int excl = part[t] - s;
    if (i0 < N) row_start[i0] = excl;
    if (i1 < N) row_start[i1] = excl + a;
    if (t == 255) blk_sum[blockIdx.x] = part[255];
}

// ---------------- stage 2 (block 0) + degree-bin scan (block 1) ----------------
__global__ __launch_bounds__(128) void scan2_kernel(const int* __restrict__ blk_sum,
                                                    int* __restrict__ blk_off,
                                                    int* __restrict__ row_start,
                                                    const int* __restrict__ dcnt,
                                                    int* __restrict__ dcur, int N) {
    __shared__ int part[128];
    int t = threadIdx.x;
    if (blockIdx.x == 0) {
        int v0 = (t < SCAN_BLOCKS) ? blk_sum[t] : 0;
        part[t] = v0;
        __syncthreads();
        for (int off = 1; off < 128; off <<= 1) {
            int v = (t >= off) ? part[t - off] : 0;
            __syncthreads();
            part[t] += v;
            __syncthreads();
        }
        blk_off[t] = part[t] - v0;
        if (t == 127) row_start[N] = part[127];
    } else {
        int v0 = (t < DBIN) ? dcnt[t] : 0;
        part[t] = v0;
        __syncthreads();
        for (int off = 1; off < DBIN; off <<= 1) {
            int v = (t >= off) ? part[t - off] : 0;
            __syncthreads();
            part[t] += v;
            __syncthreads();
        }
        if (t < DBIN) dcur[t] = part[t] - v0;   // exclusive
    }
}

// ---------------- stage 3 (blocks 0..SCAN_BLOCKS-1) + perm scatter (rest) ----------------
__global__ __launch_bounds__(256) void scan3_kernel(int* __restrict__ row_start,
                                                    const int* __restrict__ blk_off,
                                                    const int* __restrict__ cnt_in,
                                                    int* __restrict__ dcur,
                                                    int* __restrict__ perm, int N) {
    int t = threadIdx.x;
    if (blockIdx.x < SCAN_BLOCKS) {
        int base = blockIdx.x * SCAN_CHUNK;
        int off = blk_off[blockIdx.x];
        int i0 = base + 2 * t, i1 = i0 + 1;
        if (i0 < N) row_start[i0] += off;
        if (i1 < N) row_start[i1] += off;
    } else {
        __shared__ int lh[DBIN];
        __shared__ int lbase[DBIN];
        if (t < DBIN) lh[t] = 0;
        __syncthreads();
        int n = (blockIdx.x - SCAN_BLOCKS) * 256 + t;
        int bin = 0, lslot = 0;
        if (n < N) {
            bin = DBIN - 1 - min(cnt_in[n], DBIN - 1);
            lslot = atomicAdd(&lh[bin], 1);
        }
        __syncthreads();
        if (t < DBIN) lbase[t] = lh[t] ? atomicAdd(&dcur[t], lh[t]) : 0;
        __syncthreads();
        if (n < N) perm[lbase[bin] + lslot] = n;
    }
}

// ---------------- CSR fill: atomic-free ----------------
__global__ __launch_bounds__(512) void fill_kernel(const int* __restrict__ src,
                                                   const int* __restrict__ dst,
                                                   const int* __restrict__ row_start,
                                                   const unsigned int* __restrict__ partD,
                                                   const unsigned char* __restrict__ edge_slot,
                                                   int* __restrict__ csr_src) {
    int b = blockIdx.x, t = threadIdx.x;
    int base = b * HCHKE;
    size_t po = (size_t)b * NW;
    for (int i = t; i < HCHKE; i += 512) {
        int e = base + i;
        int d = dst[e];
        int cb = (int)((partD[po + (d >> 2)] >> ((d & 3) * 8)) & 0xFFu);
        csr_src[row_start[d] + cb + (int)edge_slot[e]] = src[e];
    }
}

// ---------------- staged-LDS GEMM, register-prefetch pipelined ----------------
// out[N x 96] = diag(rowScale) * A[N x K] @ W[K x 96] (+bias)
// Pipeline: issue next chunk's global loads into registers BEFORE the compute
// phase; vmcnt drain + LDS write happen after the post-compute barrier, so
// global latency hides under the ~4K-cycle FMA phase (T14 async-STAGE split).
// NOTE: no min-waves clause — R1 showed (192,3) clamps VGPR to 84 and spills
// (WRITE_SIZE 37.5->228 MB). LDS (33.8KB) limits to 4 blocks/CU regardless,
// so VGPR<=170 costs nothing.
__global__ __launch_bounds__(192) void gemm96(const float* __restrict__ A, int K,
                                              const float* __restrict__ W,
                                              const float* __restrict__ bias,
                                              const float* __restrict__ rowScale,
                                              float* __restrict__ out, int N) {
    __shared__ float A_lds[64 * 36];
    __shared__ float W_lds[32 * 96];
    const int t = threadIdx.x;
    const int row0 = blockIdx.x * 64;
    const int tcol = t % 24;
    const int trow = t / 24;
    float acc[8][4];
#pragma unroll
    for (int i = 0; i < 8; ++i)
#pragma unroll
        for (int j = 0; j < 4; ++j) acc[i][j] = 0.f;

    float4 wreg[4];
    float4 areg[3];
    float  sreg[3];

    auto loadWA = [&](int k0) {
#pragma unroll
        for (int u = 0; u < 4; ++u)
            wreg[u] = ((const float4*)W)[(size_t)k0 * 24 + t + u * 192];
#pragma unroll
        for (int u = 0; u < 3; ++u) {
            int i = t + u * 192;
            if (i < 512) {
                int r = i >> 3, kk = i & 7;
                int gr = row0 + r;
                gr = gr < N ? gr : N - 1;   // clamp: garbage rows never stored
                areg[u] = *((const float4*)(A + (size_t)gr * K + k0 + kk * 4));
                sreg[u] = rowScale ? rowScale[gr] : 1.f;
            }
        }
    };
    auto storeLDS = [&]() {
#pragma unroll
        for (int u = 0; u < 4; ++u)
            ((float4*)W_lds)[t + u * 192] = wreg[u];
#pragma unroll
        for (int u = 0; u < 3; ++u) {
            int i = t + u * 192;
            if (i < 512) {
                int r = i >> 3, kk = i & 7;
                float4 v = areg[u];
                float s = sreg[u];
                v.x *= s; v.y *= s; v.z *= s; v.w *= s;
                *((float4*)(A_lds + r * 36 + kk * 4)) = v;
            }
        }
    };

    loadWA(0);
    storeLDS();
    __syncthreads();
    for (int k0 = 0;;) {
        int kn = k0 + 32;
        bool more = kn < K;
        if (more) loadWA(kn);   // issue early; consumed after next barrier
#pragma unroll
        for (int kk4 = 0; kk4 < 8; ++kk4) {
            float4 a[8];
#pragma unroll
            for (int i = 0; i < 8; ++i)
                a[i] = *((const float4*)(A_lds + (trow + 8 * i) * 36 + kk4 * 4));
#pragma unroll
            for (int kk = 0; kk < 4; ++kk) {
                float4 wv = *((const float4*)(W_lds + (kk4 * 4 + kk) * 96 + tcol * 4));
#pragma unroll
                for (int i = 0; i < 8; ++i) {
                    float av = (kk == 0) ? a[i].x : (kk == 1) ? a[i].y : (kk == 2) ? a[i].z : a[i].w;
                    acc[i][0] = fmaf(av, wv.x, acc[i][0]);
                    acc[i][1] = fmaf(av, wv.y, acc[i][1]);
                    acc[i][2] = fmaf(av, wv.z, acc[i][2]);
                    acc[i][3] = fmaf(av, wv.w, acc[i][3]);
                }
            }
        }
        if (!more) break;
        __syncthreads();
        storeLDS();
        __syncthreads();
        k0 = kn;
    }
    float4 b4 = bias ? *((const float4*)(bias + tcol * 4)) : make_float4(0.f, 0.f, 0.f, 0.f);
#pragma unroll
    for (int i = 0; i < 8; ++i) {
        int gr = row0 + trow + 8 * i;
        if (gr < N) {
            float4 o = make_float4(acc[i][0] + b4.x, acc[i][1] + b4.y,
                                   acc[i][2] + b4.z, acc[i][3] + b4.w);
            *((float4*)(out + (size_t)gr * 96 + tcol * 4)) = o;
        }
    }
}

// ---------------- dual GEMM, register-prefetch pipelined (K=96) ----------------
__global__ __launch_bounds__(192) void gemm96x2(const float* __restrict__ A,
                                                const float* __restrict__ W1_, const float* __restrict__ b1_,
                                                const float* __restrict__ W2_, const float* __restrict__ b2_,
                                                float* __restrict__ out1, float* __restrict__ out2, int N) {
    __shared__ float A_lds[64 * 36];
    __shared__ float W_lds[2 * 32 * 96];
    const int t = threadIdx.x;
    const int row0 = blockIdx.x * 64;
    const int tcol = t % 24;
    const int trow = t / 24;
    float acc1[8][4], acc2[8][4];
#pragma unroll
    for (int i = 0; i < 8; ++i)
#pragma unroll
        for (int j = 0; j < 4; ++j) { acc1[i][j] = 0.f; acc2[i][j] = 0.f; }

    float4 wreg1[4], wreg2[4];
    float4 areg[3];

    auto loadWA = [&](int k0) {
#pragma unroll
        for (int u = 0; u < 4; ++u) {
            wreg1[u] = ((const float4*)W1_)[(size_t)k0 * 24 + t + u * 192];
            wreg2[u] = ((const float4*)W2_)[(size_t)k0 * 24 + t + u * 192];
        }
#pragma unroll
        for (int u = 0; u < 3; ++u) {
            int i = t + u * 192;
            if (i < 512) {
                int r = i >> 3, kk = i & 7;
                int gr = row0 + r;
                gr = gr < N ? gr : N - 1;   // clamp: garbage rows never stored
                areg[u] = *((const float4*)(A + (size_t)gr * 96 + k0 + kk * 4));
            }
        }
    };
    auto storeLDS = [&]() {
#pragma unroll
        for (int u = 0; u < 4; ++u) {
            ((float4*)W_lds)[t + u * 192] = wreg1[u];
            ((float4*)(W_lds + 32 * 96))[t + u * 192] = wreg2[u];
        }
#pragma unroll
        for (int u = 0; u < 3; ++u) {
            int i = t + u * 192;
            if (i < 512) {
                int r = i >> 3, kk = i & 7;
                *((float4*)(A_lds + r * 36 + kk * 4)) = areg[u];
            }
        }
    };

    loadWA(0);
    storeLDS();
    __syncthreads();
    for (int k0 = 0;;) {
        int kn = k0 + 32;
        bool more = kn < 96;
        if (more) loadWA(kn);   // issue early; consumed after next barrier
#pragma unroll
        for (int kk4 = 0; kk4 < 8; ++kk4) {
            float4 a[8];
#pragma unroll
            for (int i = 0; i < 8; ++i)
                a[i] = *((const float4*)(A_lds + (trow + 8 * i) * 36 + kk4 * 4));
#pragma unroll
            for (int kk = 0; kk < 4; ++kk) {
                float4 wv1 = *((const float4*)(W_lds + (kk4 * 4 + kk) * 96 + tcol * 4));
                float4 wv2 = *((const float4*)(W_lds + 32 * 96 + (kk4 * 4 + kk) * 96 + tcol * 4));
#pragma unroll
                for (int i = 0; i < 8; ++i) {
                    float av = (kk == 0) ? a[i].x : (kk == 1) ? a[i].y : (kk == 2) ? a[i].z : a[i].w;
                    acc1[i][0] = fmaf(av, wv1.x, acc1[i][0]);
                    acc1[i][1] = fmaf(av, wv1.y, acc1[i][1]);
                    acc1[i][2] = fmaf(av, wv1.z, acc1[i][2]);
                    acc1[i][3] = fmaf(av, wv1.w, acc1[i][3]);
                    acc2[i][0] = fmaf(av, wv2.x, acc2[i][0]);
                    acc2[i][1] = fmaf(av, wv2.y, acc2[i][1]);
                    acc2[i][2] = fmaf(av, wv2.z, acc2[i][2]);
                    acc2[i][3] = fmaf(av, wv2.w, acc2[i][3]);
                }
            }
        }
        if (!more) break;
        __syncthreads();
        storeLDS();
        __syncthreads();
        k0 = kn;
    }
    float4 bb1 = *((const float4*)(b1_ + tcol * 4));
    float4 bb2 = *((const float4*)(b2_ + tcol * 4));
#pragma unroll
    for (int i = 0; i < 8; ++i) {
        int gr = row0 + trow + 8 * i;
        if (gr < N) {
            float4 o1 = make_float4(acc1[i][0] + bb1.x, acc1[i][1] + bb1.y,
                                    acc1[i][2] + bb1.z, acc1[i][3] + bb1.w);
            float4 o2 = make_float4(acc2[i][0] + bb2.x, acc2[i][1] + bb2.y,
                                    acc2[i][2] + bb2.z, acc2[i][3] + bb2.w);
            *((float4*)(out1 + (size_t)gr * 96 + tcol * 4)) = o1;
            *((float4*)(out2 + (size_t)gr * 96 + tcol * 4)) = o2;
        }
    }
}

// ---------------- GraphConv aggregate (degree-sorted via perm) ----------------
__global__ __launch_bounds__(192) void gc_agg(const float* __restrict__ hW,
                                              const int* __restrict__ row_start,
                                              const int* __restrict__ csr_src,
                                              const float* __restrict__ degI_is,
                                              const float* __restrict__ bias,
                                              const int* __restrict__ perm,
                                              float* __restrict__ hout, int N) {
    int tid = blockIdx.x * 192 + threadIdx.x;
    int p = tid / 24;
    int c = (tid % 24) * 4;
    if (p >= N) return;
    int n = perm[p];
    int beg = row_start[n], end = row_start[n + 1];
    float4 s = make_float4(0.f, 0.f, 0.f, 0.f);
    int e = beg;
    for (; e + 4 <= end; e += 4) {
        int i0 = csr_src[e], i1 = csr_src[e + 1], i2 = csr_src[e + 2], i3 = csr_src[e + 3];
        float4 v0 = *(const float4*)(hW + (size_t)i0 * 96 + c);
        float4 v1 = *(const float4*)(hW + (size_t)i1 * 96 + c);
        float4 v2 = *(const float4*)(hW + (size_t)i2 * 96 + c);
        float4 v3 = *(const float4*)(hW + (size_t)i3 * 96 + c);
        s.x += (v0.x + v1.x) + (v2.x + v3.x);
        s.y += (v0.y + v1.y) + (v2.y + v3.y);
        s.z += (v0.z + v1.z) + (v2.z + v3.z);
        s.w += (v0.w + v1.w) + (v2.w + v3.w);
    }
    for (; e < end; ++e) {
        int i0 = csr_src[e];
        float4 v0 = *(const float4*)(hW + (size_t)i0 * 96 + c);
        s.x += v0.x; s.y += v0.y; s.z += v0.z; s.w += v0.w;
    }
    float dn = degI_is[n];
    float4 b = *(const float4*)(bias + c);
    float4 o;
    o.x = fmaxf(fmaf(s.x, dn, b.x), 0.f);
    o.y = fmaxf(fmaf(s.y, dn, b.y), 0.f);
    o.z = fmaxf(fmaf(s.z, dn, b.z), 0.f);
    o.w = fmaxf(fmaf(s.w, dn, b.w), 0.f);
    *(float4*)(hout + (size_t)n * 96 + c) = o;
}

// ---------------- GATv2: dual independent online-softmax chains, merged at end ----------------
__global__ __launch_bounds__(256) void gat_agg(const float* __restrict__ fs,
                                               const float* __restrict__ fd,
                                               const float* __restrict__ attn,
                                               const int* __restrict__ row_start,
                                               const int* __restrict__ csr_src,
                                               const int* __restrict__ perm,
                                               float* __restrict__ hout, int N) {
    int tid = blockIdx.x * 256 + threadIdx.x;
    int p = tid >> 3, hd = tid & 7;
    if (p >= N) return;
    int n = perm[p];
    float att[12], fdv[12];
    {
        const float4* ap = (const float4*)(attn + hd * 12);
        float4 a0 = ap[0], a1 = ap[1], a2 = ap[2];
        att[0]=a0.x; att[1]=a0.y; att[2]=a0.z; att[3]=a0.w;
        att[4]=a1.x; att[5]=a1.y; att[6]=a1.z; att[7]=a1.w;
        att[8]=a2.x; att[9]=a2.y; att[10]=a2.z; att[11]=a2.w;
        const float4* dp = (const float4*)(fd + (size_t)n * 96 + hd * 12);
        float4 d0 = dp[0], d1 = dp[1], d2 = dp[2];
        fdv[0]=d0.x; fdv[1]=d0.y; fdv[2]=d0.z; fdv[3]=d0.w;
        fdv[4]=d1.x; fdv[5]=d1.y; fdv[6]=d1.z; fdv[7]=d1.w;
        fdv[8]=d2.x; fdv[9]=d2.y; fdv[10]=d2.z; fdv[11]=d2.w;
    }
    int beg = row_start[n], end = row_start[n + 1];
    float m0 = -3.0e38f, den0 = 0.f, m1 = -3.0e38f, den1 = 0.f;
    float A0[12], A1[12];
#pragma unroll
    for (int d = 0; d < 12; ++d) { A0[d] = 0.f; A1[d] = 0.f; }

    auto proc = [&](const float4& s0, const float4& s1, const float4& s2,
                    float& m, float& den, float* acc) {
        float fsv[12];
        fsv[0]=s0.x; fsv[1]=s0.y; fsv[2]=s0.z; fsv[3]=s0.w;
        fsv[4]=s1.x; fsv[5]=s1.y; fsv[6]=s1.z; fsv[7]=s1.w;
        fsv[8]=s2.x; fsv[9]=s2.y; fsv[10]=s2.z; fsv[11]=s2.w;
        float logit = 0.f;
#pragma unroll
        for (int d = 0; d < 12; ++d) {
            float u = fsv[d] + fdv[d];
            u = u > 0.f ? u : 0.2f * u;
            logit = fmaf(u, att[d], logit);
        }
        float nm = fmaxf(m, logit);
        float cc = __expf(m - nm);
        float w  = __expf(logit - nm);
        den = fmaf(den, cc, w);
#pragma unroll
        for (int d = 0; d < 12; ++d) acc[d] = fmaf(acc[d], cc, w * fsv[d]);
        m = nm;
    };

    int e = beg;
    for (; e + 4 <= end; e += 4) {
        int i0 = csr_src[e], i1 = csr_src[e + 1], i2 = csr_src[e + 2], i3 = csr_src[e + 3];
        const float4* p0 = (const float4*)(fs + (size_t)i0 * 96 + hd * 12);
        const float4* p1 = (const float4*)(fs + (size_t)i1 * 96 + hd * 12);
        const float4* p2 = (const float4*)(fs + (size_t)i2 * 96 + hd * 12);
        const float4* p3 = (const float4*)(fs + (size_t)i3 * 96 + hd * 12);
        float4 a0 = p0[0], a1 = p0[1], a2 = p0[2];
        float4 b0 = p1[0], b1 = p1[1], b2 = p1[2];
        float4 c0 = p2[0], c1 = p2[1], c2 = p2[2];
        float4 d0 = p3[0], d1 = p3[1], d2 = p3[2];
        proc(a0, a1, a2, m0, den0, A0);
        proc(b0, b1, b2, m1, den1, A1);
        proc(c0, c1, c2, m0, den0, A0);
        proc(d0, d1, d2, m1, den1, A1);
    }
    for (; e < end; ++e) {
        int i0 = csr_src[e];
        const float4* p0 = (const float4*)(fs + (size_t)i0 * 96 + hd * 12);
        float4 a0 = p0[0], a1 = p0[1], a2 = p0[2];
        proc(a0, a1, a2, m0, den0, A0);
    }
    // merge the two chains
    float nm = fmaxf(m0, m1);
    float c0 = __expf(m0 - nm), c1 = __expf(m1 - nm);
    float den = den0 * c0 + den1 * c1;
    float inv = den > 0.f ? 1.f / den : 0.f;
    float* op = hout + (size_t)n * 96 + hd * 12;
#pragma unroll
    for (int d = 0; d < 12; ++d)
        op[d] = fmaxf((A0[d] * c0 + A1[d] * c1) * inv, 0.f);
}

// ---------------- per-graph max readout: stage 1, per-block LDS max -> partials ----------------
__global__ __launch_bounds__(384) void readout_partial(const float* __restrict__ h,
                                                       const int* __restrict__ graph_id,
                                                       float* __restrict__ partial, int N) {
    __shared__ int lhg[GG * 96];
    int t = threadIdx.x;
    for (int i = t; i < GG * 96; i += 384) lhg[i] = 0;
    __syncthreads();
    int f = t % 96, nl = t / 96;
    for (int n0 = blockIdx.x * 4; n0 < N; n0 += RB * 4) {
        int n = n0 + nl;
        if (n < N) {
            int g = graph_id[n];
            float v = h[(size_t)n * 96 + f];
            atomicMax(&lhg[g * 96 + f], __float_as_int(v));
        }
    }
    __syncthreads();
    for (int i = t; i < GG * 96; i += 384)
        partial[(size_t)blockIdx.x * (GG * 96) + i] = __int_as_float(lhg[i]);
}

// ---------------- readout stage 2: reduce partials ----------------
__global__ void readout_reduce(const float* __restrict__ partial, float* __restrict__ hg) {
    int i = blockIdx.x * 256 + threadIdx.x;
    if (i < GG * 96) {
        float m = 0.f;
        for (int b = 0; b < RB; ++b) m = fmaxf(m, partial[(size_t)b * (GG * 96) + i]);
        hg[i] = m;
    }
}

// ---------------- classifier MLP: one block per graph ----------------
__global__ __launch_bounds__(96) void mlp_kernel(const float* __restrict__ hg,
                                                 const float* __restrict__ Wc1, const float* __restrict__ bc1,
                                                 const float* __restrict__ Wc2, const float* __restrict__ bc2,
                                                 const float* __restrict__ Wc3, const float* __restrict__ bc3,
                                                 float* __restrict__ out) {
    int g = blockIdx.x;
    int t = threadIdx.x;
    __shared__ float z0[96], z1[96], z2[48];
    z0[t] = hg[(size_t)g * 96 + t];
    __syncthreads();
    float s = bc1[t];
    for (int k = 0; k < 96; ++k) s = fmaf(z0[k], Wc1[k * 96 + t], s);
    z1[t] = fmaxf(s, 0.f);
    __syncthreads();
    if (t < 48) {
        float s2 = bc2[t];
        for (int k = 0; k < 96; ++k) s2 = fmaf(z1[k], Wc2[k * 48 + t], s2);
        z2[t] = fmaxf(s2, 0.f);
    }
    __syncthreads();
    if (t < 10) {
        float s3 = bc3[t];
        for (int k = 0; k < 48; ++k) s3 = fmaf(z2[k], Wc3[k * 10 + t], s3);
        out[(size_t)g * 10 + t] = s3;
    }
}

extern "C" void kernel_launch(void* const* d_in, const int* in_sizes, int n_in,
                              void* d_out, int out_size, void* d_ws, size_t ws_size,
                              hipStream_t stream) {
    const float* x        = (const float*)d_in[0];
    const int*   src      = (const int*)d_in[1];
    const int*   dst      = (const int*)d_in[2];
    const int*   graph_id = (const int*)d_in[3];
    const float* W1  = (const float*)d_in[4];
    const float* b1  = (const float*)d_in[5];
    const float* W2  = (const float*)d_in[6];
    const float* b2  = (const float*)d_in[7];
    const float* Ws  = (const float*)d_in[8];
    const float* bs  = (const float*)d_in[9];
    const float* Wd  = (const float*)d_in[10];
    const float* bd  = (const float*)d_in[11];
    const float* attn = (const float*)d_in[12];
    const float* Wc1 = (const float*)d_in[13];
    const float* bc1 = (const float*)d_in[14];
    const float* Wc2 = (const float*)d_in[15];
    const float* bc2 = (const float*)d_in[16];
    const float* Wc3 = (const float*)d_in[17];
    const float* bc3 = (const float*)d_in[18];
    float* out = (float*)d_out;

    char* ws = (char*)d_ws;
    size_t off = 0;
    auto alloc = [&](size_t bytes) {
        char* p = ws + off;
        off = (off + bytes + 255) & ~(size_t)255;
        return p;
    };
    int*   cnt_in    = (int*)alloc(Nn * 4);
    int*   row_start = (int*)alloc((Nn + 1) * 4);
    unsigned char* edge_slot = (unsigned char*)alloc(Ee);
    int*   csr_src   = (int*)alloc(Ee * 4);
    int*   perm      = (int*)alloc(Nn * 4);
    float* degI_is   = (float*)alloc(Nn * 4);
    float* degO_is   = (float*)alloc(Nn * 4);
    float* bufH      = (float*)alloc((size_t)Nn * 96 * 4);
    float* bufT      = (float*)alloc((size_t)Nn * 96 * 4);
    float* bufFd     = (float*)alloc((size_t)Nn * 96 * 4);
    float* hg        = (float*)alloc(GG * 96 * 4);
    float* partial   = (float*)alloc((size_t)RB * GG * 96 * 4);
    int*   blk_sum   = (int*)alloc(128 * 4);
    int*   blk_off   = (int*)alloc(128 * 4);
    int*   dcnt      = (int*)alloc(DBIN * 4);
    int*   dcur      = (int*)alloc(DBIN * 4);

    // packed histogram partials alias the (not-yet-used) feature buffers:
    // HCHK*NW*4 = 12.8 MB each; bufT/bufFd are 19.2 MB each.
    unsigned int* partS = (unsigned int*)bufT;
    unsigned int* partD = (unsigned int*)bufFd;

    hipMemsetAsync(dcnt, 0, DBIN * 4, stream);

    // ---- CSR build + degrees + degree-sort (no global fp atomics, 6 kernels) ----
    hist_lds<<<HCHK, 512, 0, stream>>>(src, dst, partS, partD, edge_slot);
    hist_scan<<<(NW + 255) / 256, 256, 0, stream>>>(partD, partS, cnt_in, degI_is, degO_is, dcnt);
    scan1_kernel<<<SCAN_BLOCKS, 256, 0, stream>>>(cnt_in, row_start, blk_sum, Nn);
    scan2_kernel<<<2, 128, 0, stream>>>(blk_sum, blk_off, row_start, dcnt, dcur, Nn);
    scan3_kernel<<<SCAN_BLOCKS + NSB, 256, 0, stream>>>(row_start, blk_off, cnt_in, dcur, perm, Nn);
    fill_kernel<<<HCHK, 512, 0, stream>>>(src, dst, row_start, partD, edge_slot, csr_src);

    int gemm_blocks = (Nn + 63) / 64;
    int agg_blocks  = (Nn * 24 + 191) / 192;
    int gat_blocks  = (Nn * 8 + 255) / 256;

    // GraphConv 1: x[N,128] -> bufH
    gemm96<<<gemm_blocks, 192, 0, stream>>>(x, 128, W1, nullptr, degO_is, bufT, Nn);
    gc_agg<<<agg_blocks, 192, 0, stream>>>(bufT, row_start, csr_src, degI_is, b1, perm, bufH, Nn);
    // GraphConv 2
    gemm96<<<gemm_blocks, 192, 0, stream>>>(bufH, 96, W2, nullptr, degO_is, bufT, Nn);
    gc_agg<<<agg_blocks, 192, 0, stream>>>(bufT, row_start, csr_src, degI_is, b2, perm, bufH, Nn);

    // 3x GATv2: fused dual GEMM (fs,fd) then fused attention+aggregate
    for (int l = 0; l < 3; ++l) {
        const float* Wsl = Ws + (size_t)l * 96 * 96;
        const float* bsl = bs + (size_t)l * 96;
        const float* Wdl = Wd + (size_t)l * 96 * 96;
        const float* bdl = bd + (size_t)l * 96;
        const float* atl = attn + (size_t)l * 96;
        gemm96x2<<<gemm_blocks, 192, 0, stream>>>(bufH, Wsl, bsl, Wdl, bdl, bufT, bufFd, Nn);
        gat_agg<<<gat_blocks, 256, 0, stream>>>(bufT, bufFd, atl, row_start, csr_src, perm, bufH, Nn);
    }

    readout_partial<<<RB, 384, 0, stream>>>(bufH, graph_id, partial, Nn);
    readout_reduce<<<(GG * 96 + 255) / 256, 256, 0, stream>>>(partial, hg);
    mlp_kernel<<<GG, 96, 0, stream>>>(hg, Wc1, bc1, Wc2, bc2, Wc3, bc3, out);
}

// Round 3
// 656.044 us; speedup vs baseline: 1.1987x; 1.0483x over previous
//
#include <hip/hip_runtime.h>
#include <hip/hip_bf16.h>

#define Nn 50000
#define Ee 800000
#define INF_ 128
#define HIDF 96
#define HH 8
#define DD 12
#define GG 64
#define OUTF 10

#define SCAN_CHUNK 512
#define SCAN_BLOCKS ((Nn + SCAN_CHUNK - 1) / SCAN_CHUNK)   // 98
#define NSB ((Nn + 255) / 256)                             // 196
#define RB 128   // readout partial blocks

// byte-packed LDS histogram CSR build
#define HCHK 256                // edge chunks (= blocks)
#define HCHKE (Ee / HCHK)       // 3125 edges per chunk
#define NW 12512                // packed words: 4 keys/word, 50048 >= Nn
#define DBIN 64                 // degree bins for counting sort

// ---------------- hist pass A: single-pass dual byte-packed LDS histograms ----------------
__global__ __launch_bounds__(512) void hist_lds(const int* __restrict__ src,
                                                const int* __restrict__ dst,
                                                unsigned int* __restrict__ partS,
                                                unsigned int* __restrict__ partD,
                                                unsigned char* __restrict__ edge_slot) {
    __shared__ unsigned int hS[NW];
    __shared__ unsigned int hD[NW];
    int b = blockIdx.x, t = threadIdx.x;
    for (int i = t; i < NW; i += 512) { hS[i] = 0u; hD[i] = 0u; }
    __syncthreads();
    int base = b * HCHKE;
    for (int i = t; i < HCHKE; i += 512) {
        int d = dst[base + i];
        unsigned int old = atomicAdd(&hD[d >> 2], 1u << ((d & 3) * 8));
        edge_slot[base + i] = (unsigned char)((old >> ((d & 3) * 8)) & 0xFFu);
        int s = src[base + i];
        atomicAdd(&hS[s >> 2], 1u << ((s & 3) * 8));
    }
    __syncthreads();
    for (int i = t; i < NW; i += 512) {
        partD[(size_t)b * NW + i] = hD[i];
        partS[(size_t)b * NW + i] = hS[i];
    }
}

// ---------------- hist pass B ----------------
__global__ __launch_bounds__(256) void hist_scan(unsigned int* __restrict__ partD,
                                                 const unsigned int* __restrict__ partS,
                                                 int* __restrict__ cnt_in,
                                                 float* __restrict__ degI_is,
                                                 float* __restrict__ degO_is,
                                                 int* __restrict__ dcnt) {
    __shared__ int hbin[DBIN];
    int t = threadIdx.x;
    if (t < DBIN) hbin[t] = 0;
    __syncthreads();
    int w = blockIdx.x * 256 + t;
    if (w < NW) {
        unsigned int run = 0u, totS = 0u;
        for (int b = 0; b < HCHK; ++b) {
            size_t idx = (size_t)b * NW + w;
            unsigned int v = partD[idx];
            partD[idx] = run;               // exclusive prefix across chunks (packed bytes)
            run += v;
            totS += partS[idx];
        }
#pragma unroll
        for (int j = 0; j < 4; ++j) {
            int k = w * 4 + j;
            if (k < Nn) {
                int di = (int)((run >> (j * 8)) & 0xFFu);
                int dо = (int)((totS >> (j * 8)) & 0xFFu);
                cnt_in[k] = di;
                degI_is[k] = rsqrtf((float)max(di, 1));
                degO_is[k] = rsqrtf((float)max(dо, 1));
                atomicAdd(&hbin[DBIN - 1 - min(di, DBIN - 1)], 1);
            }
        }
    }
    __syncthreads();
    if (t < DBIN && hbin[t]) atomicAdd(&dcnt[t], hbin[t]);
}

// ---------------- hierarchical scan, stage 1 ----------------
__global__ __launch_bounds__(256) void scan1_kernel(const int* __restrict__ cnt,
                                                    int* __restrict__ row_start,
                                                    int* __restrict__ blk_sum, int N) {
    __shared__ int part[256];
    int t = threadIdx.x;
    int base = blockIdx.x * SCAN_CHUNK;
    int i0 = base + 2 * t, i1 = i0 + 1;
    int a = (i0 < N) ? cnt[i0] : 0;
    int b = (i1 < N) ? cnt[i1] : 0;
    int s = a + b;
    part[t] = s;
    __syncthreads();
    for (int off = 1; off < 256; off <<= 1) {
        int v = (t >= off) ? part[t - off] : 0;
        __syncthreads();
        part[t] += v;
        __syncthreads();
    }
    int excl = part[t] - s;
    if (i0 < N) row_start[i0] = excl;
    if (i1 < N) row_start[i1] = excl + a;
    if (t == 255) blk_sum[blockIdx.x] = part[255];
}

// ---------------- stage 2 (block 0) + degree-bin scan (block 1) ----------------
__global__ __launch_bounds__(128) void scan2_kernel(const int* __restrict__ blk_sum,
                                                    int* __restrict__ blk_off,
                                                    int* __restrict__ row_start,
                                                    const int* __restrict__ dcnt,
                                                    int* __restrict__ dcur, int N) {
    __shared__ int part[128];
    int t = threadIdx.x;
    if (blockIdx.x == 0) {
        int v0 = (t < SCAN_BLOCKS) ? blk_sum[t] : 0;
        part[t] = v0;
        __syncthreads();
        for (int off = 1; off < 128; off <<= 1) {
            int v = (t >= off) ? part[t - off] : 0;
            __syncthreads();
            part[t] += v;
            __syncthreads();
        }
        blk_off[t] = part[t] - v0;
        if (t == 127) row_start[N] = part[127];
    } else {
        int v0 = (t < DBIN) ? dcnt[t] : 0;
        part[t] = v0;
        __syncthreads();
        for (int off = 1; off < DBIN; off <<= 1) {
            int v = (t >= off) ? part[t - off] : 0;
            __syncthreads();
            part[t] += v;
            __syncthreads();
        }
        if (t < DBIN) dcur[t] = part[t] - v0;   // exclusive
    }
}

// ---------------- stage 3 + perm scatter ----------------
__global__ __launch_bounds__(256) void scan3_kernel(int* __restrict__ row_start,
                                                    const int* __restrict__ blk_off,
                                                    const int* __restrict__ cnt_in,
                                                    int* __restrict__ dcur,
                                                    int* __restrict__ perm, int N) {
    int t = threadIdx.x;
    if (blockIdx.x < SCAN_BLOCKS) {
        int base = blockIdx.x * SCAN_CHUNK;
        int off = blk_off[blockIdx.x];
        int i0 = base + 2 * t, i1 = i0 + 1;
        if (i0 < N) row_start[i0] += off;
        if (i1 < N) row_start[i1] += off;
    } else {
        __shared__ int lh[DBIN];
        __shared__ int lbase[DBIN];
        if (t < DBIN) lh[t] = 0;
        __syncthreads();
        int n = (blockIdx.x - SCAN_BLOCKS) * 256 + t;
        int bin = 0, lslot = 0;
        if (n < N) {
            bin = DBIN - 1 - min(cnt_in[n], DBIN - 1);
            lslot = atomicAdd(&lh[bin], 1);
        }
        __syncthreads();
        if (t < DBIN) lbase[t] = lh[t] ? atomicAdd(&dcur[t], lh[t]) : 0;
        __syncthreads();
        if (n < N) perm[lbase[bin] + lslot] = n;
    }
}

// ---------------- CSR fill: atomic-free ----------------
__global__ __launch_bounds__(512) void fill_kernel(const int* __restrict__ src,
                                                   const int* __restrict__ dst,
                                                   const int* __restrict__ row_start,
                                                   const unsigned int* __restrict__ partD,
                                                   const unsigned char* __restrict__ edge_slot,
                                                   int* __restrict__ csr_src) {
    int b = blockIdx.x, t = threadIdx.x;
    int base = b * HCHKE;
    size_t po = (size_t)b * NW;
    for (int i = t; i < HCHKE; i += 512) {
        int e = base + i;
        int d = dst[e];
        int cb = (int)((partD[po + (d >> 2)] >> ((d & 3) * 8)) & 0xFFu);
        csr_src[row_start[d] + cb + (int)edge_slot[e]] = src[e];
    }
}

// ---------------- barrier-free GEMM: W fully LDS-resident, A direct from global ----------------
// out[N x 96] = diag(rowScale) * A[N x K] @ W[K x 96] (+bias)
// R0-R2 showed the per-chunk {stage, barrier, compute, barrier} structure caps
// VALUBusy at ~20% (barrier drains) and the compiler spills any reg-prefetch
// attempt (R1: VGPR clamp 84; R2: VGPR 116 + 53MB spill). Fix: the whole W fits
// in LDS (<=49KB here, 73.7KB for x2), so load W ONCE, sync ONCE, and run the
// k-loop with ZERO barriers. A reads hit L1 (24 threads share each row -> ~3
// cache lines per wave-load). Accumulation order over k is unchanged vs R0.
__global__ __launch_bounds__(192, 1) void gemm96(const float* __restrict__ A, int K,
                                                 const float* __restrict__ W,
                                                 const float* __restrict__ bias,
                                                 const float* __restrict__ rowScale,
                                                 float* __restrict__ out, int N) {
    __shared__ float W_lds[128 * 96];   // 49152 B max (K<=128) -> 3 blocks/CU
    const int t = threadIdx.x;
    const int row0 = blockIdx.x * 64;
    const int tcol = t % 24;
    const int trow = t / 24;

    for (int i = t; i < K * 24; i += 192)
        ((float4*)W_lds)[i] = ((const float4*)W)[i];

    const float* Ap[8];
    float sc[8];
#pragma unroll
    for (int i = 0; i < 8; ++i) {
        int gr = row0 + trow + 8 * i;
        gr = gr < N ? gr : N - 1;           // clamp: garbage rows never stored
        Ap[i] = A + (size_t)gr * K;
        sc[i] = rowScale ? rowScale[gr] : 1.f;
    }
    float acc[8][4];
#pragma unroll
    for (int i = 0; i < 8; ++i)
#pragma unroll
        for (int j = 0; j < 4; ++j) acc[i][j] = 0.f;

    __syncthreads();   // the ONLY barrier

#pragma unroll 4
    for (int k = 0; k < K; k += 4) {
        float4 a[8];
#pragma unroll
        for (int i = 0; i < 8; ++i) {
            a[i] = *((const float4*)(Ap[i] + k));
            a[i].x *= sc[i]; a[i].y *= sc[i]; a[i].z *= sc[i]; a[i].w *= sc[i];
        }
#pragma unroll
        for (int kk = 0; kk < 4; ++kk) {
            float4 wv = *((const float4*)(W_lds + (k + kk) * 96 + tcol * 4));
#pragma unroll
            for (int i = 0; i < 8; ++i) {
                float av = (kk == 0) ? a[i].x : (kk == 1) ? a[i].y : (kk == 2) ? a[i].z : a[i].w;
                acc[i][0] = fmaf(av, wv.x, acc[i][0]);
                acc[i][1] = fmaf(av, wv.y, acc[i][1]);
                acc[i][2] = fmaf(av, wv.z, acc[i][2]);
                acc[i][3] = fmaf(av, wv.w, acc[i][3]);
            }
        }
    }
    float4 b4 = bias ? *((const float4*)(bias + tcol * 4)) : make_float4(0.f, 0.f, 0.f, 0.f);
#pragma unroll
    for (int i = 0; i < 8; ++i) {
        int gr = row0 + trow + 8 * i;
        if (gr < N) {
            float4 o = make_float4(acc[i][0] + b4.x, acc[i][1] + b4.y,
                                   acc[i][2] + b4.z, acc[i][3] + b4.w);
            *((float4*)(out + (size_t)gr * 96 + tcol * 4)) = o;
        }
    }
}

// ---------------- barrier-free dual GEMM (K=96): both weight matrices LDS-resident ----------------
__global__ __launch_bounds__(192, 1) void gemm96x2(const float* __restrict__ A,
                                                   const float* __restrict__ W1_, const float* __restrict__ b1_,
                                                   const float* __restrict__ W2_, const float* __restrict__ b2_,
                                                   float* __restrict__ out1, float* __restrict__ out2, int N) {
    __shared__ float W_lds[2 * 96 * 96];   // 73728 B -> 2 blocks/CU (LDS-bound)
    const int t = threadIdx.x;
    const int row0 = blockIdx.x * 64;
    const int tcol = t % 24;
    const int trow = t / 24;

    for (int i = t; i < 96 * 24; i += 192) {
        ((float4*)W_lds)[i] = ((const float4*)W1_)[i];
        ((float4*)(W_lds + 96 * 96))[i] = ((const float4*)W2_)[i];
    }

    const float* Ap[8];
#pragma unroll
    for (int i = 0; i < 8; ++i) {
        int gr = row0 + trow + 8 * i;
        gr = gr < N ? gr : N - 1;           // clamp: garbage rows never stored
        Ap[i] = A + (size_t)gr * 96;
    }
    float acc1[8][4], acc2[8][4];
#pragma unroll
    for (int i = 0; i < 8; ++i)
#pragma unroll
        for (int j = 0; j < 4; ++j) { acc1[i][j] = 0.f; acc2[i][j] = 0.f; }

    __syncthreads();   // the ONLY barrier

#pragma unroll 2
    for (int k = 0; k < 96; k += 4) {
        float4 a[8];
#pragma unroll
        for (int i = 0; i < 8; ++i)
            a[i] = *((const float4*)(Ap[i] + k));
#pragma unroll
        for (int kk = 0; kk < 4; ++kk) {
            float4 wv1 = *((const float4*)(W_lds + (k + kk) * 96 + tcol * 4));
            float4 wv2 = *((const float4*)(W_lds + 96 * 96 + (k + kk) * 96 + tcol * 4));
#pragma unroll
            for (int i = 0; i < 8; ++i) {
                float av = (kk == 0) ? a[i].x : (kk == 1) ? a[i].y : (kk == 2) ? a[i].z : a[i].w;
                acc1[i][0] = fmaf(av, wv1.x, acc1[i][0]);
                acc1[i][1] = fmaf(av, wv1.y, acc1[i][1]);
                acc1[i][2] = fmaf(av, wv1.z, acc1[i][2]);
                acc1[i][3] = fmaf(av, wv1.w, acc1[i][3]);
                acc2[i][0] = fmaf(av, wv2.x, acc2[i][0]);
                acc2[i][1] = fmaf(av, wv2.y, acc2[i][1]);
                acc2[i][2] = fmaf(av, wv2.z, acc2[i][2]);
                acc2[i][3] = fmaf(av, wv2.w, acc2[i][3]);
            }
        }
    }
    float4 bb1 = *((const float4*)(b1_ + tcol * 4));
    float4 bb2 = *((const float4*)(b2_ + tcol * 4));
#pragma unroll
    for (int i = 0; i < 8; ++i) {
        int gr = row0 + trow + 8 * i;
        if (gr < N) {
            float4 o1 = make_float4(acc1[i][0] + bb1.x, acc1[i][1] + bb1.y,
                                    acc1[i][2] + bb1.z, acc1[i][3] + bb1.w);
            float4 o2 = make_float4(acc2[i][0] + bb2.x, acc2[i][1] + bb2.y,
                                    acc2[i][2] + bb2.z, acc2[i][3] + bb2.w);
            *((float4*)(out1 + (size_t)gr * 96 + tcol * 4)) = o1;
            *((float4*)(out2 + (size_t)gr * 96 + tcol * 4)) = o2;
        }
    }
}

// ---------------- GraphConv aggregate (degree-sorted via perm) ----------------
__global__ __launch_bounds__(192) void gc_agg(const float* __restrict__ hW,
                                              const int* __restrict__ row_start,
                                              const int* __restrict__ csr_src,
                                              const float* __restrict__ degI_is,
                                              const float* __restrict__ bias,
                                              const int* __restrict__ perm,
                                              float* __restrict__ hout, int N) {
    int tid = blockIdx.x * 192 + threadIdx.x;
    int p = tid / 24;
    int c = (tid % 24) * 4;
    if (p >= N) return;
    int n = perm[p];
    int beg = row_start[n], end = row_start[n + 1];
    float4 s = make_float4(0.f, 0.f, 0.f, 0.f);
    int e = beg;
    for (; e + 4 <= end; e += 4) {
        int i0 = csr_src[e], i1 = csr_src[e + 1], i2 = csr_src[e + 2], i3 = csr_src[e + 3];
        float4 v0 = *(const float4*)(hW + (size_t)i0 * 96 + c);
        float4 v1 = *(const float4*)(hW + (size_t)i1 * 96 + c);
        float4 v2 = *(const float4*)(hW + (size_t)i2 * 96 + c);
        float4 v3 = *(const float4*)(hW + (size_t)i3 * 96 + c);
        s.x += (v0.x + v1.x) + (v2.x + v3.x);
        s.y += (v0.y + v1.y) + (v2.y + v3.y);
        s.z += (v0.z + v1.z) + (v2.z + v3.z);
        s.w += (v0.w + v1.w) + (v2.w + v3.w);
    }
    for (; e < end; ++e) {
        int i0 = csr_src[e];
        float4 v0 = *(const float4*)(hW + (size_t)i0 * 96 + c);
        s.x += v0.x; s.y += v0.y; s.z += v0.z; s.w += v0.w;
    }
    float dn = degI_is[n];
    float4 b = *(const float4*)(bias + c);
    float4 o;
    o.x = fmaxf(fmaf(s.x, dn, b.x), 0.f);
    o.y = fmaxf(fmaf(s.y, dn, b.y), 0.f);
    o.z = fmaxf(fmaf(s.z, dn, b.z), 0.f);
    o.w = fmaxf(fmaf(s.w, dn, b.w), 0.f);
    *(float4*)(hout + (size_t)n * 96 + c) = o;
}

// ---------------- GATv2: dual independent online-softmax chains, merged at end ----------------
__global__ __launch_bounds__(256) void gat_agg(const float* __restrict__ fs,
                                               const float* __restrict__ fd,
                                               const float* __restrict__ attn,
                                               const int* __restrict__ row_start,
                                               const int* __restrict__ csr_src,
                                               const int* __restrict__ perm,
                                               float* __restrict__ hout, int N) {
    int tid = blockIdx.x * 256 + threadIdx.x;
    int p = tid >> 3, hd = tid & 7;
    if (p >= N) return;
    int n = perm[p];
    float att[12], fdv[12];
    {
        const float4* ap = (const float4*)(attn + hd * 12);
        float4 a0 = ap[0], a1 = ap[1], a2 = ap[2];
        att[0]=a0.x; att[1]=a0.y; att[2]=a0.z; att[3]=a0.w;
        att[4]=a1.x; att[5]=a1.y; att[6]=a1.z; att[7]=a1.w;
        att[8]=a2.x; att[9]=a2.y; att[10]=a2.z; att[11]=a2.w;
        const float4* dp = (const float4*)(fd + (size_t)n * 96 + hd * 12);
        float4 d0 = dp[0], d1 = dp[1], d2 = dp[2];
        fdv[0]=d0.x; fdv[1]=d0.y; fdv[2]=d0.z; fdv[3]=d0.w;
        fdv[4]=d1.x; fdv[5]=d1.y; fdv[6]=d1.z; fdv[7]=d1.w;
        fdv[8]=d2.x; fdv[9]=d2.y; fdv[10]=d2.z; fdv[11]=d2.w;
    }
    int beg = row_start[n], end = row_start[n + 1];
    float m0 = -3.0e38f, den0 = 0.f, m1 = -3.0e38f, den1 = 0.f;
    float A0[12], A1[12];
#pragma unroll
    for (int d = 0; d < 12; ++d) { A0[d] = 0.f; A1[d] = 0.f; }

    auto proc = [&](const float4& s0, const float4& s1, const float4& s2,
                    float& m, float& den, float* acc) {
        float fsv[12];
        fsv[0]=s0.x; fsv[1]=s0.y; fsv[2]=s0.z; fsv[3]=s0.w;
        fsv[4]=s1.x; fsv[5]=s1.y; fsv[6]=s1.z; fsv[7]=s1.w;
        fsv[8]=s2.x; fsv[9]=s2.y; fsv[10]=s2.z; fsv[11]=s2.w;
        float logit = 0.f;
#pragma unroll
        for (int d = 0; d < 12; ++d) {
            float u = fsv[d] + fdv[d];
            u = u > 0.f ? u : 0.2f * u;
            logit = fmaf(u, att[d], logit);
        }
        float nm = fmaxf(m, logit);
        float cc = __expf(m - nm);
        float w  = __expf(logit - nm);
        den = fmaf(den, cc, w);
#pragma unroll
        for (int d = 0; d < 12; ++d) acc[d] = fmaf(acc[d], cc, w * fsv[d]);
        m = nm;
    };

    int e = beg;
    for (; e + 4 <= end; e += 4) {
        int i0 = csr_src[e], i1 = csr_src[e + 1], i2 = csr_src[e + 2], i3 = csr_src[e + 3];
        const float4* p0 = (const float4*)(fs + (size_t)i0 * 96 + hd * 12);
        const float4* p1 = (const float4*)(fs + (size_t)i1 * 96 + hd * 12);
        const float4* p2 = (const float4*)(fs + (size_t)i2 * 96 + hd * 12);
        const float4* p3 = (const float4*)(fs + (size_t)i3 * 96 + hd * 12);
        float4 a0 = p0[0], a1 = p0[1], a2 = p0[2];
        float4 b0 = p1[0], b1 = p1[1], b2 = p1[2];
        float4 c0 = p2[0], c1 = p2[1], c2 = p2[2];
        float4 d0 = p3[0], d1 = p3[1], d2 = p3[2];
        proc(a0, a1, a2, m0, den0, A0);
        proc(b0, b1, b2, m1, den1, A1);
        proc(c0, c1, c2, m0, den0, A0);
        proc(d0, d1, d2, m1, den1, A1);
    }
    for (; e < end; ++e) {
        int i0 = csr_src[e];
        const float4* p0 = (const float4*)(fs + (size_t)i0 * 96 + hd * 12);
        float4 a0 = p0[0], a1 = p0[1], a2 = p0[2];
        proc(a0, a1, a2, m0, den0, A0);
    }
    // merge the two chains
    float nm = fmaxf(m0, m1);
    float c0 = __expf(m0 - nm), c1 = __expf(m1 - nm);
    float den = den0 * c0 + den1 * c1;
    float inv = den > 0.f ? 1.f / den : 0.f;
    float* op = hout + (size_t)n * 96 + hd * 12;
#pragma unroll
    for (int d = 0; d < 12; ++d)
        op[d] = fmaxf((A0[d] * c0 + A1[d] * c1) * inv, 0.f);
}

// ---------------- per-graph max readout: stage 1 ----------------
__global__ __launch_bounds__(384) void readout_partial(const float* __restrict__ h,
                                                       const int* __restrict__ graph_id,
                                                       float* __restrict__ partial, int N) {
    __shared__ int lhg[GG * 96];
    int t = threadIdx.x;
    for (int i = t; i < GG * 96; i += 384) lhg[i] = 0;
    __syncthreads();
    int f = t % 96, nl = t / 96;
    for (int n0 = blockIdx.x * 4; n0 < N; n0 += RB * 4) {
        int n = n0 + nl;
        if (n < N) {
            int g = graph_id[n];
            float v = h[(size_t)n * 96 + f];
            atomicMax(&lhg[g * 96 + f], __float_as_int(v));
        }
    }
    __syncthreads();
    for (int i = t; i < GG * 96; i += 384)
        partial[(size_t)blockIdx.x * (GG * 96) + i] = __int_as_float(lhg[i]);
}

// ---------------- readout stage 2: reduce partials ----------------
__global__ void readout_reduce(const float* __restrict__ partial, float* __restrict__ hg) {
    int i = blockIdx.x * 256 + threadIdx.x;
    if (i < GG * 96) {
        float m = 0.f;
        for (int b = 0; b < RB; ++b) m = fmaxf(m, partial[(size_t)b * (GG * 96) + i]);
        hg[i] = m;
    }
}

// ---------------- classifier MLP: one block per graph ----------------
__global__ __launch_bounds__(96) void mlp_kernel(const float* __restrict__ hg,
                                                 const float* __restrict__ Wc1, const float* __restrict__ bc1,
                                                 const float* __restrict__ Wc2, const float* __restrict__ bc2,
                                                 const float* __restrict__ Wc3, const float* __restrict__ bc3,
                                                 float* __restrict__ out) {
    int g = blockIdx.x;
    int t = threadIdx.x;
    __shared__ float z0[96], z1[96], z2[48];
    z0[t] = hg[(size_t)g * 96 + t];
    __syncthreads();
    float s = bc1[t];
    for (int k = 0; k < 96; ++k) s = fmaf(z0[k], Wc1[k * 96 + t], s);
    z1[t] = fmaxf(s, 0.f);
    __syncthreads();
    if (t < 48) {
        float s2 = bc2[t];
        for (int k = 0; k < 96; ++k) s2 = fmaf(z1[k], Wc2[k * 48 + t], s2);
        z2[t] = fmaxf(s2, 0.f);
    }
    __syncthreads();
    if (t < 10) {
        float s3 = bc3[t];
        for (int k = 0; k < 48; ++k) s3 = fmaf(z2[k], Wc3[k * 10 + t], s3);
        out[(size_t)g * 10 + t] = s3;
    }
}

extern "C" void kernel_launch(void* const* d_in, const int* in_sizes, int n_in,
                              void* d_out, int out_size, void* d_ws, size_t ws_size,
                              hipStream_t stream) {
    const float* x        = (const float*)d_in[0];
    const int*   src      = (const int*)d_in[1];
    const int*   dst      = (const int*)d_in[2];
    const int*   graph_id = (const int*)d_in[3];
    const float* W1  = (const float*)d_in[4];
    const float* b1  = (const float*)d_in[5];
    const float* W2  = (const float*)d_in[6];
    const float* b2  = (const float*)d_in[7];
    const float* Ws  = (const float*)d_in[8];
    const float* bs  = (const float*)d_in[9];
    const float* Wd  = (const float*)d_in[10];
    const float* bd  = (const float*)d_in[11];
    const float* attn = (const float*)d_in[12];
    const float* Wc1 = (const float*)d_in[13];
    const float* bc1 = (const float*)d_in[14];
    const float* Wc2 = (const float*)d_in[15];
    const float* bc2 = (const float*)d_in[16];
    const float* Wc3 = (const float*)d_in[17];
    const float* bc3 = (const float*)d_in[18];
    float* out = (float*)d_out;

    char* ws = (char*)d_ws;
    size_t off = 0;
    auto alloc = [&](size_t bytes) {
        char* p = ws + off;
        off = (off + bytes + 255) & ~(size_t)255;
        return p;
    };
    int*   cnt_in    = (int*)alloc(Nn * 4);
    int*   row_start = (int*)alloc((Nn + 1) * 4);
    unsigned char* edge_slot = (unsigned char*)alloc(Ee);
    int*   csr_src   = (int*)alloc(Ee * 4);
    int*   perm      = (int*)alloc(Nn * 4);
    float* degI_is   = (float*)alloc(Nn * 4);
    float* degO_is   = (float*)alloc(Nn * 4);
    float* bufH      = (float*)alloc((size_t)Nn * 96 * 4);
    float* bufT      = (float*)alloc((size_t)Nn * 96 * 4);
    float* bufFd     = (float*)alloc((size_t)Nn * 96 * 4);
    float* hg        = (float*)alloc(GG * 96 * 4);
    float* partial   = (float*)alloc((size_t)RB * GG * 96 * 4);
    int*   blk_sum   = (int*)alloc(128 * 4);
    int*   blk_off   = (int*)alloc(128 * 4);
    int*   dcnt      = (int*)alloc(DBIN * 4);
    int*   dcur      = (int*)alloc(DBIN * 4);

    // packed histogram partials alias the (not-yet-used) feature buffers:
    // HCHK*NW*4 = 12.8 MB each; bufT/bufFd are 19.2 MB each.
    unsigned int* partS = (unsigned int*)bufT;
    unsigned int* partD = (unsigned int*)bufFd;

    hipMemsetAsync(dcnt, 0, DBIN * 4, stream);

    // ---- CSR build + degrees + degree-sort (no global fp atomics, 6 kernels) ----
    hist_lds<<<HCHK, 512, 0, stream>>>(src, dst, partS, partD, edge_slot);
    hist_scan<<<(NW + 255) / 256, 256, 0, stream>>>(partD, partS, cnt_in, degI_is, degO_is, dcnt);
    scan1_kernel<<<SCAN_BLOCKS, 256, 0, stream>>>(cnt_in, row_start, blk_sum, Nn);
    scan2_kernel<<<2, 128, 0, stream>>>(blk_sum, blk_off, row_start, dcnt, dcur, Nn);
    scan3_kernel<<<SCAN_BLOCKS + NSB, 256, 0, stream>>>(row_start, blk_off, cnt_in, dcur, perm, Nn);
    fill_kernel<<<HCHK, 512, 0, stream>>>(src, dst, row_start, partD, edge_slot, csr_src);

    int gemm_blocks = (Nn + 63) / 64;
    int agg_blocks  = (Nn * 24 + 191) / 192;
    int gat_blocks  = (Nn * 8 + 255) / 256;

    // GraphConv 1: x[N,128] -> bufH
    gemm96<<<gemm_blocks, 192, 0, stream>>>(x, 128, W1, nullptr, degO_is, bufT, Nn);
    gc_agg<<<agg_blocks, 192, 0, stream>>>(bufT, row_start, csr_src, degI_is, b1, perm, bufH, Nn);
    // GraphConv 2
    gemm96<<<gemm_blocks, 192, 0, stream>>>(bufH, 96, W2, nullptr, degO_is, bufT, Nn);
    gc_agg<<<agg_blocks, 192, 0, stream>>>(bufT, row_start, csr_src, degI_is, b2, perm, bufH, Nn);

    // 3x GATv2: fused dual GEMM (fs,fd) then fused attention+aggregate
    for (int l = 0; l < 3; ++l) {
        const float* Wsl = Ws + (size_t)l * 96 * 96;
        const float* bsl = bs + (size_t)l * 96;
        const float* Wdl = Wd + (size_t)l * 96 * 96;
        const float* bdl = bd + (size_t)l * 96;
        const float* atl = attn + (size_t)l * 96;
        gemm96x2<<<gemm_blocks, 192, 0, stream>>>(bufH, Wsl, bsl, Wdl, bdl, bufT, bufFd, Nn);
        gat_agg<<<gat_blocks, 256, 0, stream>>>(bufT, bufFd, atl, row_start, csr_src, perm, bufH, Nn);
    }

    readout_partial<<<RB, 384, 0, stream>>>(bufH, graph_id, partial, Nn);
    readout_reduce<<<(GG * 96 + 255) / 256, 256, 0, stream>>>(partial, hg);
    mlp_kernel<<<GG, 96, 0, stream>>>(hg, Wc1, bc1, Wc2, bc2, Wc3, bc3, out);
}

// Round 4
// 645.685 us; speedup vs baseline: 1.2179x; 1.0160x over previous
//
#include <hip/hip_runtime.h>
#include <hip/hip_bf16.h>

#define Nn 50000
#define Ee 800000
#define INF_ 128
#define HIDF 96
#define HH 8
#define DD 12
#define GG 64
#define OUTF 10

#define SCAN_CHUNK 512
#define SCAN_BLOCKS ((Nn + SCAN_CHUNK - 1) / SCAN_CHUNK)   // 98
#define NSB ((Nn + 255) / 256)                             // 196
#define RB 128   // readout partial blocks

// byte-packed LDS histogram CSR build
#define HCHK 256                // edge chunks (= blocks)
#define HCHKE (Ee / HCHK)       // 3125 edges per chunk
#define NW 12512                // packed words: 4 keys/word, 50048 >= Nn
#define DBIN 64                 // degree bins for counting sort

// ---------------- hist pass A: single-pass dual byte-packed LDS histograms ----------------
__global__ __launch_bounds__(512) void hist_lds(const int* __restrict__ src,
                                                const int* __restrict__ dst,
                                                unsigned int* __restrict__ partS,
                                                unsigned int* __restrict__ partD,
                                                unsigned char* __restrict__ edge_slot) {
    __shared__ unsigned int hS[NW];
    __shared__ unsigned int hD[NW];
    int b = blockIdx.x, t = threadIdx.x;
    for (int i = t; i < NW; i += 512) { hS[i] = 0u; hD[i] = 0u; }
    __syncthreads();
    int base = b * HCHKE;
    for (int i = t; i < HCHKE; i += 512) {
        int d = dst[base + i];
        unsigned int old = atomicAdd(&hD[d >> 2], 1u << ((d & 3) * 8));
        edge_slot[base + i] = (unsigned char)((old >> ((d & 3) * 8)) & 0xFFu);
        int s = src[base + i];
        atomicAdd(&hS[s >> 2], 1u << ((s & 3) * 8));
    }
    __syncthreads();
    for (int i = t; i < NW; i += 512) {
        partD[(size_t)b * NW + i] = hD[i];
        partS[(size_t)b * NW + i] = hS[i];
    }
}

// ---------------- hist pass B ----------------
__global__ __launch_bounds__(256) void hist_scan(unsigned int* __restrict__ partD,
                                                 const unsigned int* __restrict__ partS,
                                                 int* __restrict__ cnt_in,
                                                 float* __restrict__ degI_is,
                                                 float* __restrict__ degO_is,
                                                 int* __restrict__ dcnt) {
    __shared__ int hbin[DBIN];
    int t = threadIdx.x;
    if (t < DBIN) hbin[t] = 0;
    __syncthreads();
    int w = blockIdx.x * 256 + t;
    if (w < NW) {
        unsigned int run = 0u, totS = 0u;
        for (int b = 0; b < HCHK; ++b) {
            size_t idx = (size_t)b * NW + w;
            unsigned int v = partD[idx];
            partD[idx] = run;               // exclusive prefix across chunks (packed bytes)
            run += v;
            totS += partS[idx];
        }
#pragma unroll
        for (int j = 0; j < 4; ++j) {
            int k = w * 4 + j;
            if (k < Nn) {
                int di = (int)((run >> (j * 8)) & 0xFFu);
                int dо = (int)((totS >> (j * 8)) & 0xFFu);
                cnt_in[k] = di;
                degI_is[k] = rsqrtf((float)max(di, 1));
                degO_is[k] = rsqrtf((float)max(dо, 1));
                atomicAdd(&hbin[DBIN - 1 - min(di, DBIN - 1)], 1);
            }
        }
    }
    __syncthreads();
    if (t < DBIN && hbin[t]) atomicAdd(&dcnt[t], hbin[t]);
}

// ---------------- hierarchical scan, stage 1 ----------------
__global__ __launch_bounds__(256) void scan1_kernel(const int* __restrict__ cnt,
                                                    int* __restrict__ row_start,
                                                    int* __restrict__ blk_sum, int N) {
    __shared__ int part[256];
    int t = threadIdx.x;
    int base = blockIdx.x * SCAN_CHUNK;
    int i0 = base + 2 * t, i1 = i0 + 1;
    int a = (i0 < N) ? cnt[i0] : 0;
    int b = (i1 < N) ? cnt[i1] : 0;
    int s = a + b;
    part[t] = s;
    __syncthreads();
    for (int off = 1; off < 256; off <<= 1) {
        int v = (t >= off) ? part[t - off] : 0;
        __syncthreads();
        part[t] += v;
        __syncthreads();
    }
    int excl = part[t] - s;
    if (i0 < N) row_start[i0] = excl;
    if (i1 < N) row_start[i1] = excl + a;
    if (t == 255) blk_sum[blockIdx.x] = part[255];
}

// ---------------- stage 2 (block 0) + degree-bin scan (block 1) ----------------
__global__ __launch_bounds__(128) void scan2_kernel(const int* __restrict__ blk_sum,
                                                    int* __restrict__ blk_off,
                                                    int* __restrict__ row_start,
                                                    const int* __restrict__ dcnt,
                                                    int* __restrict__ dcur, int N) {
    __shared__ int part[128];
    int t = threadIdx.x;
    if (blockIdx.x == 0) {
        int v0 = (t < SCAN_BLOCKS) ? blk_sum[t] : 0;
        part[t] = v0;
        __syncthreads();
        for (int off = 1; off < 128; off <<= 1) {
            int v = (t >= off) ? part[t - off] : 0;
            __syncthreads();
            part[t] += v;
            __syncthreads();
        }
        blk_off[t] = part[t] - v0;
        if (t == 127) row_start[N] = part[127];
    } else {
        int v0 = (t < DBIN) ? dcnt[t] : 0;
        part[t] = v0;
        __syncthreads();
        for (int off = 1; off < DBIN; off <<= 1) {
            int v = (t >= off) ? part[t - off] : 0;
            __syncthreads();
            part[t] += v;
            __syncthreads();
        }
        if (t < DBIN) dcur[t] = part[t] - v0;   // exclusive
    }
}

// ---------------- stage 3 + perm scatter ----------------
__global__ __launch_bounds__(256) void scan3_kernel(int* __restrict__ row_start,
                                                    const int* __restrict__ blk_off,
                                                    const int* __restrict__ cnt_in,
                                                    int* __restrict__ dcur,
                                                    int* __restrict__ perm, int N) {
    int t = threadIdx.x;
    if (blockIdx.x < SCAN_BLOCKS) {
        int base = blockIdx.x * SCAN_CHUNK;
        int off = blk_off[blockIdx.x];
        int i0 = base + 2 * t, i1 = i0 + 1;
        if (i0 < N) row_start[i0] += off;
        if (i1 < N) row_start[i1] += off;
    } else {
        __shared__ int lh[DBIN];
        __shared__ int lbase[DBIN];
        if (t < DBIN) lh[t] = 0;
        __syncthreads();
        int n = (blockIdx.x - SCAN_BLOCKS) * 256 + t;
        int bin = 0, lslot = 0;
        if (n < N) {
            bin = DBIN - 1 - min(cnt_in[n], DBIN - 1);
            lslot = atomicAdd(&lh[bin], 1);
        }
        __syncthreads();
        if (t < DBIN) lbase[t] = lh[t] ? atomicAdd(&dcur[t], lh[t]) : 0;
        __syncthreads();
        if (n < N) perm[lbase[bin] + lslot] = n;
    }
}

// ---------------- CSR fill: atomic-free ----------------
__global__ __launch_bounds__(512) void fill_kernel(const int* __restrict__ src,
                                                   const int* __restrict__ dst,
                                                   const int* __restrict__ row_start,
                                                   const unsigned int* __restrict__ partD,
                                                   const unsigned char* __restrict__ edge_slot,
                                                   int* __restrict__ csr_src) {
    int b = blockIdx.x, t = threadIdx.x;
    int base = b * HCHKE;
    size_t po = (size_t)b * NW;
    for (int i = t; i < HCHKE; i += 512) {
        int e = base + i;
        int d = dst[e];
        int cb = (int)((partD[po + (d >> 2)] >> ((d & 3) * 8)) & 0xFFu);
        csr_src[row_start[d] + cb + (int)edge_slot[e]] = src[e];
    }
}

// ---------------- barrier-free GEMM + register double-buffered A-prefetch ----------------
// out[N x 96] = diag(rowScale) * A[N x K] @ W[K x 96] (+bias)
// R3 showed the barrier-free W-resident structure is spill-free but the compiler
// (VGPR=96) exposes the full A-load latency every 4-k chunk: VALUBusy ~20% =
// 300cy compute / (900cy L2-cross-XCD/HBM latency + 300). Fix: manual 1-deep
// register double-buffer — next chunk's 8 A-loads are always in flight under
// the current chunk's FMA phase. Static buffer names only (no runtime-indexed
// arrays -> no scratch). LDS caps occupancy at 3 blocks/CU, so VGPR up to ~256
// is free.
__global__ __launch_bounds__(192, 1) void gemm96(const float* __restrict__ A, int K,
                                                 const float* __restrict__ W,
                                                 const float* __restrict__ bias,
                                                 const float* __restrict__ rowScale,
                                                 float* __restrict__ out, int N) {
    __shared__ float W_lds[128 * 96];   // 49152 B max (K<=128) -> 3 blocks/CU
    const int t = threadIdx.x;
    const int row0 = blockIdx.x * 64;
    const int tcol = t % 24;
    const int trow = t / 24;

    for (int i = t; i < K * 24; i += 192)
        ((float4*)W_lds)[i] = ((const float4*)W)[i];

    const float* Ap[8];
    float sc[8];
#pragma unroll
    for (int i = 0; i < 8; ++i) {
        int gr = row0 + trow + 8 * i;
        gr = gr < N ? gr : N - 1;           // clamp: garbage rows never stored
        Ap[i] = A + (size_t)gr * K;
        sc[i] = rowScale ? rowScale[gr] : 1.f;
    }
    float acc[8][4];
#pragma unroll
    for (int i = 0; i < 8; ++i)
#pragma unroll
        for (int j = 0; j < 4; ++j) acc[i][j] = 0.f;

    float4 bufA[8], bufB[8];
#pragma unroll
    for (int i = 0; i < 8; ++i) bufA[i] = *((const float4*)(Ap[i]));   // k=0

    __syncthreads();   // the ONLY barrier

    auto compute = [&](const float4* a, int k) {
#pragma unroll
        for (int kk = 0; kk < 4; ++kk) {
            float4 wv = *((const float4*)(W_lds + (k + kk) * 96 + tcol * 4));
#pragma unroll
            for (int i = 0; i < 8; ++i) {
                float av = ((kk == 0) ? a[i].x : (kk == 1) ? a[i].y
                           : (kk == 2) ? a[i].z : a[i].w) * sc[i];
                acc[i][0] = fmaf(av, wv.x, acc[i][0]);
                acc[i][1] = fmaf(av, wv.y, acc[i][1]);
                acc[i][2] = fmaf(av, wv.z, acc[i][2]);
                acc[i][3] = fmaf(av, wv.w, acc[i][3]);
            }
        }
    };

    for (int k = 0; k + 8 <= K; k += 8) {
#pragma unroll
        for (int i = 0; i < 8; ++i) bufB[i] = *((const float4*)(Ap[i] + k + 4));
        compute(bufA, k);
        if (k + 8 < K) {
#pragma unroll
            for (int i = 0; i < 8; ++i) bufA[i] = *((const float4*)(Ap[i] + k + 8));
        }
        compute(bufB, k + 4);
    }
    float4 b4 = bias ? *((const float4*)(bias + tcol * 4)) : make_float4(0.f, 0.f, 0.f, 0.f);
#pragma unroll
    for (int i = 0; i < 8; ++i) {
        int gr = row0 + trow + 8 * i;
        if (gr < N) {
            float4 o = make_float4(acc[i][0] + b4.x, acc[i][1] + b4.y,
                                   acc[i][2] + b4.z, acc[i][3] + b4.w);
            *((float4*)(out + (size_t)gr * 96 + tcol * 4)) = o;
        }
    }
}

// ---------------- barrier-free dual GEMM (K=96) + register double-buffered A-prefetch ----------------
__global__ __launch_bounds__(192, 1) void gemm96x2(const float* __restrict__ A,
                                                   const float* __restrict__ W1_, const float* __restrict__ b1_,
                                                   const float* __restrict__ W2_, const float* __restrict__ b2_,
                                                   float* __restrict__ out1, float* __restrict__ out2, int N) {
    __shared__ float W_lds[2 * 96 * 96];   // 73728 B -> 2 blocks/CU (LDS-bound)
    const int t = threadIdx.x;
    const int row0 = blockIdx.x * 64;
    const int tcol = t % 24;
    const int trow = t / 24;

    for (int i = t; i < 96 * 24; i += 192) {
        ((float4*)W_lds)[i] = ((const float4*)W1_)[i];
        ((float4*)(W_lds + 96 * 96))[i] = ((const float4*)W2_)[i];
    }

    const float* Ap[8];
#pragma unroll
    for (int i = 0; i < 8; ++i) {
        int gr = row0 + trow + 8 * i;
        gr = gr < N ? gr : N - 1;           // clamp: garbage rows never stored
        Ap[i] = A + (size_t)gr * 96;
    }
    float acc1[8][4], acc2[8][4];
#pragma unroll
    for (int i = 0; i < 8; ++i)
#pragma unroll
        for (int j = 0; j < 4; ++j) { acc1[i][j] = 0.f; acc2[i][j] = 0.f; }

    float4 bufA[8], bufB[8];
#pragma unroll
    for (int i = 0; i < 8; ++i) bufA[i] = *((const float4*)(Ap[i]));   // k=0

    __syncthreads();   // the ONLY barrier

    auto compute = [&](const float4* a, int k) {
#pragma unroll
        for (int kk = 0; kk < 4; ++kk) {
            float4 wv1 = *((const float4*)(W_lds + (k + kk) * 96 + tcol * 4));
            float4 wv2 = *((const float4*)(W_lds + 96 * 96 + (k + kk) * 96 + tcol * 4));
#pragma unroll
            for (int i = 0; i < 8; ++i) {
                float av = (kk == 0) ? a[i].x : (kk == 1) ? a[i].y : (kk == 2) ? a[i].z : a[i].w;
                acc1[i][0] = fmaf(av, wv1.x, acc1[i][0]);
                acc1[i][1] = fmaf(av, wv1.y, acc1[i][1]);
                acc1[i][2] = fmaf(av, wv1.z, acc1[i][2]);
                acc1[i][3] = fmaf(av, wv1.w, acc1[i][3]);
                acc2[i][0] = fmaf(av, wv2.x, acc2[i][0]);
                acc2[i][1] = fmaf(av, wv2.y, acc2[i][1]);
                acc2[i][2] = fmaf(av, wv2.z, acc2[i][2]);
                acc2[i][3] = fmaf(av, wv2.w, acc2[i][3]);
            }
        }
    };

    for (int k = 0; k + 8 <= 96; k += 8) {
#pragma unroll
        for (int i = 0; i < 8; ++i) bufB[i] = *((const float4*)(Ap[i] + k + 4));
        compute(bufA, k);
        if (k + 8 < 96) {
#pragma unroll
            for (int i = 0; i < 8; ++i) bufA[i] = *((const float4*)(Ap[i] + k + 8));
        }
        compute(bufB, k + 4);
    }
    float4 bb1 = *((const float4*)(b1_ + tcol * 4));
    float4 bb2 = *((const float4*)(b2_ + tcol * 4));
#pragma unroll
    for (int i = 0; i < 8; ++i) {
        int gr = row0 + trow + 8 * i;
        if (gr < N) {
            float4 o1 = make_float4(acc1[i][0] + bb1.x, acc1[i][1] + bb1.y,
                                    acc1[i][2] + bb1.z, acc1[i][3] + bb1.w);
            float4 o2 = make_float4(acc2[i][0] + bb2.x, acc2[i][1] + bb2.y,
                                    acc2[i][2] + bb2.z, acc2[i][3] + bb2.w);
            *((float4*)(out1 + (size_t)gr * 96 + tcol * 4)) = o1;
            *((float4*)(out2 + (size_t)gr * 96 + tcol * 4)) = o2;
        }
    }
}

// ---------------- GraphConv aggregate (degree-sorted via perm) ----------------
__global__ __launch_bounds__(192) void gc_agg(const float* __restrict__ hW,
                                              const int* __restrict__ row_start,
                                              const int* __restrict__ csr_src,
                                              const float* __restrict__ degI_is,
                                              const float* __restrict__ bias,
                                              const int* __restrict__ perm,
                                              float* __restrict__ hout, int N) {
    int tid = blockIdx.x * 192 + threadIdx.x;
    int p = tid / 24;
    int c = (tid % 24) * 4;
    if (p >= N) return;
    int n = perm[p];
    int beg = row_start[n], end = row_start[n + 1];
    float4 s = make_float4(0.f, 0.f, 0.f, 0.f);
    int e = beg;
    for (; e + 4 <= end; e += 4) {
        int i0 = csr_src[e], i1 = csr_src[e + 1], i2 = csr_src[e + 2], i3 = csr_src[e + 3];
        float4 v0 = *(const float4*)(hW + (size_t)i0 * 96 + c);
        float4 v1 = *(const float4*)(hW + (size_t)i1 * 96 + c);
        float4 v2 = *(const float4*)(hW + (size_t)i2 * 96 + c);
        float4 v3 = *(const float4*)(hW + (size_t)i3 * 96 + c);
        s.x += (v0.x + v1.x) + (v2.x + v3.x);
        s.y += (v0.y + v1.y) + (v2.y + v3.y);
        s.z += (v0.z + v1.z) + (v2.z + v3.z);
        s.w += (v0.w + v1.w) + (v2.w + v3.w);
    }
    for (; e < end; ++e) {
        int i0 = csr_src[e];
        float4 v0 = *(const float4*)(hW + (size_t)i0 * 96 + c);
        s.x += v0.x; s.y += v0.y; s.z += v0.z; s.w += v0.w;
    }
    float dn = degI_is[n];
    float4 b = *(const float4*)(bias + c);
    float4 o;
    o.x = fmaxf(fmaf(s.x, dn, b.x), 0.f);
    o.y = fmaxf(fmaf(s.y, dn, b.y), 0.f);
    o.z = fmaxf(fmaf(s.z, dn, b.z), 0.f);
    o.w = fmaxf(fmaf(s.w, dn, b.w), 0.f);
    *(float4*)(hout + (size_t)n * 96 + c) = o;
}

// ---------------- GATv2: dual independent online-softmax chains, merged at end ----------------
__global__ __launch_bounds__(256) void gat_agg(const float* __restrict__ fs,
                                               const float* __restrict__ fd,
                                               const float* __restrict__ attn,
                                               const int* __restrict__ row_start,
                                               const int* __restrict__ csr_src,
                                               const int* __restrict__ perm,
                                               float* __restrict__ hout, int N) {
    int tid = blockIdx.x * 256 + threadIdx.x;
    int p = tid >> 3, hd = tid & 7;
    if (p >= N) return;
    int n = perm[p];
    float att[12], fdv[12];
    {
        const float4* ap = (const float4*)(attn + hd * 12);
        float4 a0 = ap[0], a1 = ap[1], a2 = ap[2];
        att[0]=a0.x; att[1]=a0.y; att[2]=a0.z; att[3]=a0.w;
        att[4]=a1.x; att[5]=a1.y; att[6]=a1.z; att[7]=a1.w;
        att[8]=a2.x; att[9]=a2.y; att[10]=a2.z; att[11]=a2.w;
        const float4* dp = (const float4*)(fd + (size_t)n * 96 + hd * 12);
        float4 d0 = dp[0], d1 = dp[1], d2 = dp[2];
        fdv[0]=d0.x; fdv[1]=d0.y; fdv[2]=d0.z; fdv[3]=d0.w;
        fdv[4]=d1.x; fdv[5]=d1.y; fdv[6]=d1.z; fdv[7]=d1.w;
        fdv[8]=d2.x; fdv[9]=d2.y; fdv[10]=d2.z; fdv[11]=d2.w;
    }
    int beg = row_start[n], end = row_start[n + 1];
    float m0 = -3.0e38f, den0 = 0.f, m1 = -3.0e38f, den1 = 0.f;
    float A0[12], A1[12];
#pragma unroll
    for (int d = 0; d < 12; ++d) { A0[d] = 0.f; A1[d] = 0.f; }

    auto proc = [&](const float4& s0, const float4& s1, const float4& s2,
                    float& m, float& den, float* acc) {
        float fsv[12];
        fsv[0]=s0.x; fsv[1]=s0.y; fsv[2]=s0.z; fsv[3]=s0.w;
        fsv[4]=s1.x; fsv[5]=s1.y; fsv[6]=s1.z; fsv[7]=s1.w;
        fsv[8]=s2.x; fsv[9]=s2.y; fsv[10]=s2.z; fsv[11]=s2.w;
        float logit = 0.f;
#pragma unroll
        for (int d = 0; d < 12; ++d) {
            float u = fsv[d] + fdv[d];
            u = u > 0.f ? u : 0.2f * u;
            logit = fmaf(u, att[d], logit);
        }
        float nm = fmaxf(m, logit);
        float cc = __expf(m - nm);
        float w  = __expf(logit - nm);
        den = fmaf(den, cc, w);
#pragma unroll
        for (int d = 0; d < 12; ++d) acc[d] = fmaf(acc[d], cc, w * fsv[d]);
        m = nm;
    };

    int e = beg;
    for (; e + 4 <= end; e += 4) {
        int i0 = csr_src[e], i1 = csr_src[e + 1], i2 = csr_src[e + 2], i3 = csr_src[e + 3];
        const float4* p0 = (const float4*)(fs + (size_t)i0 * 96 + hd * 12);
        const float4* p1 = (const float4*)(fs + (size_t)i1 * 96 + hd * 12);
        const float4* p2 = (const float4*)(fs + (size_t)i2 * 96 + hd * 12);
        const float4* p3 = (const float4*)(fs + (size_t)i3 * 96 + hd * 12);
        float4 a0 = p0[0], a1 = p0[1], a2 = p0[2];
        float4 b0 = p1[0], b1 = p1[1], b2 = p1[2];
        float4 c0 = p2[0], c1 = p2[1], c2 = p2[2];
        float4 d0 = p3[0], d1 = p3[1], d2 = p3[2];
        proc(a0, a1, a2, m0, den0, A0);
        proc(b0, b1, b2, m1, den1, A1);
        proc(c0, c1, c2, m0, den0, A0);
        proc(d0, d1, d2, m1, den1, A1);
    }
    for (; e < end; ++e) {
        int i0 = csr_src[e];
        const float4* p0 = (const float4*)(fs + (size_t)i0 * 96 + hd * 12);
        float4 a0 = p0[0], a1 = p0[1], a2 = p0[2];
        proc(a0, a1, a2, m0, den0, A0);
    }
    // merge the two chains
    float nm = fmaxf(m0, m1);
    float c0 = __expf(m0 - nm), c1 = __expf(m1 - nm);
    float den = den0 * c0 + den1 * c1;
    float inv = den > 0.f ? 1.f / den : 0.f;
    float* op = hout + (size_t)n * 96 + hd * 12;
#pragma unroll
    for (int d = 0; d < 12; ++d)
        op[d] = fmaxf((A0[d] * c0 + A1[d] * c1) * inv, 0.f);
}

// ---------------- per-graph max readout: stage 1 ----------------
__global__ __launch_bounds__(384) void readout_partial(const float* __restrict__ h,
                                                       const int* __restrict__ graph_id,
                                                       float* __restrict__ partial, int N) {
    __shared__ int lhg[GG * 96];
    int t = threadIdx.x;
    for (int i = t; i < GG * 96; i += 384) lhg[i] = 0;
    __syncthreads();
    int f = t % 96, nl = t / 96;
    for (int n0 = blockIdx.x * 4; n0 < N; n0 += RB * 4) {
        int n = n0 + nl;
        if (n < N) {
            int g = graph_id[n];
            float v = h[(size_t)n * 96 + f];
            atomicMax(&lhg[g * 96 + f], __float_as_int(v));
        }
    }
    __syncthreads();
    for (int i = t; i < GG * 96; i += 384)
        partial[(size_t)blockIdx.x * (GG * 96) + i] = __int_as_float(lhg[i]);
}

// ---------------- readout stage 2: reduce partials ----------------
__global__ void readout_reduce(const float* __restrict__ partial, float* __restrict__ hg) {
    int i = blockIdx.x * 256 + threadIdx.x;
    if (i < GG * 96) {
        float m = 0.f;
        for (int b = 0; b < RB; ++b) m = fmaxf(m, partial[(size_t)b * (GG * 96) + i]);
        hg[i] = m;
    }
}

// ---------------- classifier MLP: one block per graph ----------------
__global__ __launch_bounds__(96) void mlp_kernel(const float* __restrict__ hg,
                                                 const float* __restrict__ Wc1, const float* __restrict__ bc1,
                                                 const float* __restrict__ Wc2, const float* __restrict__ bc2,
                                                 const float* __restrict__ Wc3, const float* __restrict__ bc3,
                                                 float* __restrict__ out) {
    int g = blockIdx.x;
    int t = threadIdx.x;
    __shared__ float z0[96], z1[96], z2[48];
    z0[t] = hg[(size_t)g * 96 + t];
    __syncthreads();
    float s = bc1[t];
    for (int k = 0; k < 96; ++k) s = fmaf(z0[k], Wc1[k * 96 + t], s);
    z1[t] = fmaxf(s, 0.f);
    __syncthreads();
    if (t < 48) {
        float s2 = bc2[t];
        for (int k = 0; k < 96; ++k) s2 = fmaf(z1[k], Wc2[k * 48 + t], s2);
        z2[t] = fmaxf(s2, 0.f);
    }
    __syncthreads();
    if (t < 10) {
        float s3 = bc3[t];
        for (int k = 0; k < 48; ++k) s3 = fmaf(z2[k], Wc3[k * 10 + t], s3);
        out[(size_t)g * 10 + t] = s3;
    }
}

extern "C" void kernel_launch(void* const* d_in, const int* in_sizes, int n_in,
                              void* d_out, int out_size, void* d_ws, size_t ws_size,
                              hipStream_t stream) {
    const float* x        = (const float*)d_in[0];
    const int*   src      = (const int*)d_in[1];
    const int*   dst      = (const int*)d_in[2];
    const int*   graph_id = (const int*)d_in[3];
    const float* W1  = (const float*)d_in[4];
    const float* b1  = (const float*)d_in[5];
    const float* W2  = (const float*)d_in[6];
    const float* b2  = (const float*)d_in[7];
    const float* Ws  = (const float*)d_in[8];
    const float* bs  = (const float*)d_in[9];
    const float* Wd  = (const float*)d_in[10];
    const float* bd  = (const float*)d_in[11];
    const float* attn = (const float*)d_in[12];
    const float* Wc1 = (const float*)d_in[13];
    const float* bc1 = (const float*)d_in[14];
    const float* Wc2 = (const float*)d_in[15];
    const float* bc2 = (const float*)d_in[16];
    const float* Wc3 = (const float*)d_in[17];
    const float* bc3 = (const float*)d_in[18];
    float* out = (float*)d_out;

    char* ws = (char*)d_ws;
    size_t off = 0;
    auto alloc = [&](size_t bytes) {
        char* p = ws + off;
        off = (off + bytes + 255) & ~(size_t)255;
        return p;
    };
    int*   cnt_in    = (int*)alloc(Nn * 4);
    int*   row_start = (int*)alloc((Nn + 1) * 4);
    unsigned char* edge_slot = (unsigned char*)alloc(Ee);
    int*   csr_src   = (int*)alloc(Ee * 4);
    int*   perm      = (int*)alloc(Nn * 4);
    float* degI_is   = (float*)alloc(Nn * 4);
    float* degO_is   = (float*)alloc(Nn * 4);
    float* bufH      = (float*)alloc((size_t)Nn * 96 * 4);
    float* bufT      = (float*)alloc((size_t)Nn * 96 * 4);
    float* bufFd     = (float*)alloc((size_t)Nn * 96 * 4);
    float* hg        = (float*)alloc(GG * 96 * 4);
    float* partial   = (float*)alloc((size_t)RB * GG * 96 * 4);
    int*   blk_sum   = (int*)alloc(128 * 4);
    int*   blk_off   = (int*)alloc(128 * 4);
    int*   dcnt      = (int*)alloc(DBIN * 4);
    int*   dcur      = (int*)alloc(DBIN * 4);

    // packed histogram partials alias the (not-yet-used) feature buffers:
    // HCHK*NW*4 = 12.8 MB each; bufT/bufFd are 19.2 MB each.
    unsigned int* partS = (unsigned int*)bufT;
    unsigned int* partD = (unsigned int*)bufFd;

    hipMemsetAsync(dcnt, 0, DBIN * 4, stream);

    // ---- CSR build + degrees + degree-sort (no global fp atomics, 6 kernels) ----
    hist_lds<<<HCHK, 512, 0, stream>>>(src, dst, partS, partD, edge_slot);
    hist_scan<<<(NW + 255) / 256, 256, 0, stream>>>(partD, partS, cnt_in, degI_is, degO_is, dcnt);
    scan1_kernel<<<SCAN_BLOCKS, 256, 0, stream>>>(cnt_in, row_start, blk_sum, Nn);
    scan2_kernel<<<2, 128, 0, stream>>>(blk_sum, blk_off, row_start, dcnt, dcur, Nn);
    scan3_kernel<<<SCAN_BLOCKS + NSB, 256, 0, stream>>>(row_start, blk_off, cnt_in, dcur, perm, Nn);
    fill_kernel<<<HCHK, 512, 0, stream>>>(src, dst, row_start, partD, edge_slot, csr_src);

    int gemm_blocks = (Nn + 63) / 64;
    int agg_blocks  = (Nn * 24 + 191) / 192;
    int gat_blocks  = (Nn * 8 + 255) / 256;

    // GraphConv 1: x[N,128] -> bufH
    gemm96<<<gemm_blocks, 192, 0, stream>>>(x, 128, W1, nullptr, degO_is, bufT, Nn);
    gc_agg<<<agg_blocks, 192, 0, stream>>>(bufT, row_start, csr_src, degI_is, b1, perm, bufH, Nn);
    // GraphConv 2
    gemm96<<<gemm_blocks, 192, 0, stream>>>(bufH, 96, W2, nullptr, degO_is, bufT, Nn);
    gc_agg<<<agg_blocks, 192, 0, stream>>>(bufT, row_start, csr_src, degI_is, b2, perm, bufH, Nn);

    // 3x GATv2: fused dual GEMM (fs,fd) then fused attention+aggregate
    for (int l = 0; l < 3; ++l) {
        const float* Wsl = Ws + (size_t)l * 96 * 96;
        const float* bsl = bs + (size_t)l * 96;
        const float* Wdl = Wd + (size_t)l * 96 * 96;
        const float* bdl = bd + (size_t)l * 96;
        const float* atl = attn + (size_t)l * 96;
        gemm96x2<<<gemm_blocks, 192, 0, stream>>>(bufH, Wsl, bsl, Wdl, bdl, bufT, bufFd, Nn);
        gat_agg<<<gat_blocks, 256, 0, stream>>>(bufT, bufFd, atl, row_start, csr_src, perm, bufH, Nn);
    }

    readout_partial<<<RB, 384, 0, stream>>>(bufH, graph_id, partial, Nn);
    readout_reduce<<<(GG * 96 + 255) / 256, 256, 0, stream>>>(partial, hg);
    mlp_kernel<<<GG, 96, 0, stream>>>(hg, Wc1, bc1, Wc2, bc2, Wc3, bc3, out);
}

// Round 5
// 639.986 us; speedup vs baseline: 1.2287x; 1.0089x over previous
//
#include <hip/hip_runtime.h>
#include <hip/hip_bf16.h>

#define Nn 50000
#define Ee 800000
#define INF_ 128
#define HIDF 96
#define HH 8
#define DD 12
#define GG 64
#define OUTF 10

#define SCAN_CHUNK 512
#define SCAN_BLOCKS ((Nn + SCAN_CHUNK - 1) / SCAN_CHUNK)   // 98
#define NSB ((Nn + 255) / 256)                             // 196
#define RB 128   // readout partial blocks

// byte-packed LDS histogram CSR build
#define HCHK 256                // edge chunks (= blocks)
#define HCHKE (Ee / HCHK)       // 3125 edges per chunk
#define NW 12512                // packed words: 4 keys/word, 50048 >= Nn
#define DBIN 64                 // degree bins for counting sort

// ---------------- hist pass A: single-pass dual byte-packed LDS histograms ----------------
__global__ __launch_bounds__(512) void hist_lds(const int* __restrict__ src,
                                                const int* __restrict__ dst,
                                                unsigned int* __restrict__ partS,
                                                unsigned int* __restrict__ partD,
                                                unsigned char* __restrict__ edge_slot) {
    __shared__ unsigned int hS[NW];
    __shared__ unsigned int hD[NW];
    int b = blockIdx.x, t = threadIdx.x;
    for (int i = t; i < NW; i += 512) { hS[i] = 0u; hD[i] = 0u; }
    __syncthreads();
    int base = b * HCHKE;
    for (int i = t; i < HCHKE; i += 512) {
        int d = dst[base + i];
        unsigned int old = atomicAdd(&hD[d >> 2], 1u << ((d & 3) * 8));
        edge_slot[base + i] = (unsigned char)((old >> ((d & 3) * 8)) & 0xFFu);
        int s = src[base + i];
        atomicAdd(&hS[s >> 2], 1u << ((s & 3) * 8));
    }
    __syncthreads();
    for (int i = t; i < NW; i += 512) {
        partD[(size_t)b * NW + i] = hD[i];
        partS[(size_t)b * NW + i] = hS[i];
    }
}

// ---------------- hist pass B ----------------
__global__ __launch_bounds__(256) void hist_scan(unsigned int* __restrict__ partD,
                                                 const unsigned int* __restrict__ partS,
                                                 int* __restrict__ cnt_in,
                                                 float* __restrict__ degI_is,
                                                 float* __restrict__ degO_is,
                                                 int* __restrict__ dcnt) {
    __shared__ int hbin[DBIN];
    int t = threadIdx.x;
    if (t < DBIN) hbin[t] = 0;
    __syncthreads();
    int w = blockIdx.x * 256 + t;
    if (w < NW) {
        unsigned int run = 0u, totS = 0u;
        for (int b = 0; b < HCHK; ++b) {
            size_t idx = (size_t)b * NW + w;
            unsigned int v = partD[idx];
            partD[idx] = run;               // exclusive prefix across chunks (packed bytes)
            run += v;
            totS += partS[idx];
        }
#pragma unroll
        for (int j = 0; j < 4; ++j) {
            int k = w * 4 + j;
            if (k < Nn) {
                int di = (int)((run >> (j * 8)) & 0xFFu);
                int dо = (int)((totS >> (j * 8)) & 0xFFu);
                cnt_in[k] = di;
                degI_is[k] = rsqrtf((float)max(di, 1));
                degO_is[k] = rsqrtf((float)max(dо, 1));
                atomicAdd(&hbin[DBIN - 1 - min(di, DBIN - 1)], 1);
            }
        }
    }
    __syncthreads();
    if (t < DBIN && hbin[t]) atomicAdd(&dcnt[t], hbin[t]);
}

// ---------------- hierarchical scan, stage 1 ----------------
__global__ __launch_bounds__(256) void scan1_kernel(const int* __restrict__ cnt,
                                                    int* __restrict__ row_start,
                                                    int* __restrict__ blk_sum, int N) {
    __shared__ int part[256];
    int t = threadIdx.x;
    int base = blockIdx.x * SCAN_CHUNK;
    int i0 = base + 2 * t, i1 = i0 + 1;
    int a = (i0 < N) ? cnt[i0] : 0;
    int b = (i1 < N) ? cnt[i1] : 0;
    int s = a + b;
    part[t] = s;
    __syncthreads();
    for (int off = 1; off < 256; off <<= 1) {
        int v = (t >= off) ? part[t - off] : 0;
        __syncthreads();
        part[t] += v;
        __syncthreads();
    }
    int excl = part[t] - s;
    if (i0 < N) row_start[i0] = excl;
    if (i1 < N) row_start[i1] = excl + a;
    if (t == 255) blk_sum[blockIdx.x] = part[255];
}

// ---------------- stage 2 (block 0) + degree-bin scan (block 1) ----------------
__global__ __launch_bounds__(128) void scan2_kernel(const int* __restrict__ blk_sum,
                                                    int* __restrict__ blk_off,
                                                    int* __restrict__ row_start,
                                                    const int* __restrict__ dcnt,
                                                    int* __restrict__ dcur, int N) {
    __shared__ int part[128];
    int t = threadIdx.x;
    if (blockIdx.x == 0) {
        int v0 = (t < SCAN_BLOCKS) ? blk_sum[t] : 0;
        part[t] = v0;
        __syncthreads();
        for (int off = 1; off < 128; off <<= 1) {
            int v = (t >= off) ? part[t - off] : 0;
            __syncthreads();
            part[t] += v;
            __syncthreads();
        }
        blk_off[t] = part[t] - v0;
        if (t == 127) row_start[N] = part[127];
    } else {
        int v0 = (t < DBIN) ? dcnt[t] : 0;
        part[t] = v0;
        __syncthreads();
        for (int off = 1; off < DBIN; off <<= 1) {
            int v = (t >= off) ? part[t - off] : 0;
            __syncthreads();
            part[t] += v;
            __syncthreads();
        }
        if (t < DBIN) dcur[t] = part[t] - v0;   // exclusive
    }
}

// ---------------- stage 3 + perm scatter ----------------
__global__ __launch_bounds__(256) void scan3_kernel(int* __restrict__ row_start,
                                                    const int* __restrict__ blk_off,
                                                    const int* __restrict__ cnt_in,
                                                    int* __restrict__ dcur,
                                                    int* __restrict__ perm, int N) {
    int t = threadIdx.x;
    if (blockIdx.x < SCAN_BLOCKS) {
        int base = blockIdx.x * SCAN_CHUNK;
        int off = blk_off[blockIdx.x];
        int i0 = base + 2 * t, i1 = i0 + 1;
        if (i0 < N) row_start[i0] += off;
        if (i1 < N) row_start[i1] += off;
    } else {
        __shared__ int lh[DBIN];
        __shared__ int lbase[DBIN];
        if (t < DBIN) lh[t] = 0;
        __syncthreads();
        int n = (blockIdx.x - SCAN_BLOCKS) * 256 + t;
        int bin = 0, lslot = 0;
        if (n < N) {
            bin = DBIN - 1 - min(cnt_in[n], DBIN - 1);
            lslot = atomicAdd(&lh[bin], 1);
        }
        __syncthreads();
        if (t < DBIN) lbase[t] = lh[t] ? atomicAdd(&dcur[t], lh[t]) : 0;
        __syncthreads();
        if (n < N) perm[lbase[bin] + lslot] = n;
    }
}

// ---------------- CSR fill: atomic-free ----------------
__global__ __launch_bounds__(512) void fill_kernel(const int* __restrict__ src,
                                                   const int* __restrict__ dst,
                                                   const int* __restrict__ row_start,
                                                   const unsigned int* __restrict__ partD,
                                                   const unsigned char* __restrict__ edge_slot,
                                                   int* __restrict__ csr_src) {
    int b = blockIdx.x, t = threadIdx.x;
    int base = b * HCHKE;
    size_t po = (size_t)b * NW;
    for (int i = t; i < HCHKE; i += 512) {
        int e = base + i;
        int d = dst[e];
        int cb = (int)((partD[po + (d >> 2)] >> ((d & 3) * 8)) & 0xFFu);
        csr_src[row_start[d] + cb + (int)edge_slot[e]] = src[e];
    }
}

// ---------------- barrier-free GEMM + register double-buffered A-prefetch ----------------
__global__ __launch_bounds__(192, 1) void gemm96(const float* __restrict__ A, int K,
                                                 const float* __restrict__ W,
                                                 const float* __restrict__ bias,
                                                 const float* __restrict__ rowScale,
                                                 float* __restrict__ out, int N) {
    __shared__ float W_lds[128 * 96];   // 49152 B max (K<=128) -> 3 blocks/CU
    const int t = threadIdx.x;
    const int row0 = blockIdx.x * 64;
    const int tcol = t % 24;
    const int trow = t / 24;

    for (int i = t; i < K * 24; i += 192)
        ((float4*)W_lds)[i] = ((const float4*)W)[i];

    const float* Ap[8];
    float sc[8];
#pragma unroll
    for (int i = 0; i < 8; ++i) {
        int gr = row0 + trow + 8 * i;
        gr = gr < N ? gr : N - 1;           // clamp: garbage rows never stored
        Ap[i] = A + (size_t)gr * K;
        sc[i] = rowScale ? rowScale[gr] : 1.f;
    }
    float acc[8][4];
#pragma unroll
    for (int i = 0; i < 8; ++i)
#pragma unroll
        for (int j = 0; j < 4; ++j) acc[i][j] = 0.f;

    float4 bufA[8], bufB[8];
#pragma unroll
    for (int i = 0; i < 8; ++i) bufA[i] = *((const float4*)(Ap[i]));   // k=0

    __syncthreads();   // the ONLY barrier

    auto compute = [&](const float4* a, int k) {
#pragma unroll
        for (int kk = 0; kk < 4; ++kk) {
            float4 wv = *((const float4*)(W_lds + (k + kk) * 96 + tcol * 4));
#pragma unroll
            for (int i = 0; i < 8; ++i) {
                float av = ((kk == 0) ? a[i].x : (kk == 1) ? a[i].y
                           : (kk == 2) ? a[i].z : a[i].w) * sc[i];
                acc[i][0] = fmaf(av, wv.x, acc[i][0]);
                acc[i][1] = fmaf(av, wv.y, acc[i][1]);
                acc[i][2] = fmaf(av, wv.z, acc[i][2]);
                acc[i][3] = fmaf(av, wv.w, acc[i][3]);
            }
        }
    };

    for (int k = 0; k + 8 <= K; k += 8) {
#pragma unroll
        for (int i = 0; i < 8; ++i) bufB[i] = *((const float4*)(Ap[i] + k + 4));
        compute(bufA, k);
        if (k + 8 < K) {
#pragma unroll
            for (int i = 0; i < 8; ++i) bufA[i] = *((const float4*)(Ap[i] + k + 8));
        }
        compute(bufB, k + 4);
    }
    float4 b4 = bias ? *((const float4*)(bias + tcol * 4)) : make_float4(0.f, 0.f, 0.f, 0.f);
#pragma unroll
    for (int i = 0; i < 8; ++i) {
        int gr = row0 + trow + 8 * i;
        if (gr < N) {
            float4 o = make_float4(acc[i][0] + b4.x, acc[i][1] + b4.y,
                                   acc[i][2] + b4.z, acc[i][3] + b4.w);
            *((float4*)(out + (size_t)gr * 96 + tcol * 4)) = o;
        }
    }
}

// ---------------- barrier-free dual GEMM (K=96) + register double-buffered A-prefetch ----------------
__global__ __launch_bounds__(192, 1) void gemm96x2(const float* __restrict__ A,
                                                   const float* __restrict__ W1_, const float* __restrict__ b1_,
                                                   const float* __restrict__ W2_, const float* __restrict__ b2_,
                                                   float* __restrict__ out1, float* __restrict__ out2, int N) {
    __shared__ float W_lds[2 * 96 * 96];   // 73728 B -> 2 blocks/CU (LDS-bound)
    const int t = threadIdx.x;
    const int row0 = blockIdx.x * 64;
    const int tcol = t % 24;
    const int trow = t / 24;

    for (int i = t; i < 96 * 24; i += 192) {
        ((float4*)W_lds)[i] = ((const float4*)W1_)[i];
        ((float4*)(W_lds + 96 * 96))[i] = ((const float4*)W2_)[i];
    }

    const float* Ap[8];
#pragma unroll
    for (int i = 0; i < 8; ++i) {
        int gr = row0 + trow + 8 * i;
        gr = gr < N ? gr : N - 1;           // clamp: garbage rows never stored
        Ap[i] = A + (size_t)gr * 96;
    }
    float acc1[8][4], acc2[8][4];
#pragma unroll
    for (int i = 0; i < 8; ++i)
#pragma unroll
        for (int j = 0; j < 4; ++j) { acc1[i][j] = 0.f; acc2[i][j] = 0.f; }

    float4 bufA[8], bufB[8];
#pragma unroll
    for (int i = 0; i < 8; ++i) bufA[i] = *((const float4*)(Ap[i]));   // k=0

    __syncthreads();   // the ONLY barrier

    auto compute = [&](const float4* a, int k) {
#pragma unroll
        for (int kk = 0; kk < 4; ++kk) {
            float4 wv1 = *((const float4*)(W_lds + (k + kk) * 96 + tcol * 4));
            float4 wv2 = *((const float4*)(W_lds + 96 * 96 + (k + kk) * 96 + tcol * 4));
#pragma unroll
            for (int i = 0; i < 8; ++i) {
                float av = (kk == 0) ? a[i].x : (kk == 1) ? a[i].y : (kk == 2) ? a[i].z : a[i].w;
                acc1[i][0] = fmaf(av, wv1.x, acc1[i][0]);
                acc1[i][1] = fmaf(av, wv1.y, acc1[i][1]);
                acc1[i][2] = fmaf(av, wv1.z, acc1[i][2]);
                acc1[i][3] = fmaf(av, wv1.w, acc1[i][3]);
                acc2[i][0] = fmaf(av, wv2.x, acc2[i][0]);
                acc2[i][1] = fmaf(av, wv2.y, acc2[i][1]);
                acc2[i][2] = fmaf(av, wv2.z, acc2[i][2]);
                acc2[i][3] = fmaf(av, wv2.w, acc2[i][3]);
            }
        }
    };

    for (int k = 0; k + 8 <= 96; k += 8) {
#pragma unroll
        for (int i = 0; i < 8; ++i) bufB[i] = *((const float4*)(Ap[i] + k + 4));
        compute(bufA, k);
        if (k + 8 < 96) {
#pragma unroll
            for (int i = 0; i < 8; ++i) bufA[i] = *((const float4*)(Ap[i] + k + 8));
        }
        compute(bufB, k + 4);
    }
    float4 bb1 = *((const float4*)(b1_ + tcol * 4));
    float4 bb2 = *((const float4*)(b2_ + tcol * 4));
#pragma unroll
    for (int i = 0; i < 8; ++i) {
        int gr = row0 + trow + 8 * i;
        if (gr < N) {
            float4 o1 = make_float4(acc1[i][0] + bb1.x, acc1[i][1] + bb1.y,
                                    acc1[i][2] + bb1.z, acc1[i][3] + bb1.w);
            float4 o2 = make_float4(acc2[i][0] + bb2.x, acc2[i][1] + bb2.y,
                                    acc2[i][2] + bb2.z, acc2[i][3] + bb2.w);
            *((float4*)(out1 + (size_t)gr * 96 + tcol * 4)) = o1;
            *((float4*)(out2 + (size_t)gr * 96 + tcol * 4)) = o2;
        }
    }
}

// ---------------- GraphConv aggregate (degree-sorted via perm) ----------------
__global__ __launch_bounds__(192) void gc_agg(const float* __restrict__ hW,
                                              const int* __restrict__ row_start,
                                              const int* __restrict__ csr_src,
                                              const float* __restrict__ degI_is,
                                              const float* __restrict__ bias,
                                              const int* __restrict__ perm,
                                              float* __restrict__ hout, int N) {
    int tid = blockIdx.x * 192 + threadIdx.x;
    int p = tid / 24;
    int c = (tid % 24) * 4;
    if (p >= N) return;
    int n = perm[p];
    int beg = row_start[n], end = row_start[n + 1];
    float4 s = make_float4(0.f, 0.f, 0.f, 0.f);
    int e = beg;
    for (; e + 4 <= end; e += 4) {
        int i0 = csr_src[e], i1 = csr_src[e + 1], i2 = csr_src[e + 2], i3 = csr_src[e + 3];
        float4 v0 = *(const float4*)(hW + (size_t)i0 * 96 + c);
        float4 v1 = *(const float4*)(hW + (size_t)i1 * 96 + c);
        float4 v2 = *(const float4*)(hW + (size_t)i2 * 96 + c);
        float4 v3 = *(const float4*)(hW + (size_t)i3 * 96 + c);
        s.x += (v0.x + v1.x) + (v2.x + v3.x);
        s.y += (v0.y + v1.y) + (v2.y + v3.y);
        s.z += (v0.z + v1.z) + (v2.z + v3.z);
        s.w += (v0.w + v1.w) + (v2.w + v3.w);
    }
    for (; e < end; ++e) {
        int i0 = csr_src[e];
        float4 v0 = *(const float4*)(hW + (size_t)i0 * 96 + c);
        s.x += v0.x; s.y += v0.y; s.z += v0.z; s.w += v0.w;
    }
    float dn = degI_is[n];
    float4 b = *(const float4*)(bias + c);
    float4 o;
    o.x = fmaxf(fmaf(s.x, dn, b.x), 0.f);
    o.y = fmaxf(fmaf(s.y, dn, b.y), 0.f);
    o.z = fmaxf(fmaf(s.z, dn, b.z), 0.f);
    o.w = fmaxf(fmaf(s.w, dn, b.w), 0.f);
    *(float4*)(hout + (size_t)n * 96 + c) = o;
}

// ---------------- GATv2: 4-way edge-split per (node, head), shfl_xor butterfly merge ----------------
// R4: gat_agg latency-bound (VALUBusy 26%, Occ 32%, 2.7 TB/s read). One thread
// per (node,head) gave only 1563 blocks and a serial online-softmax chain ->
// too few outstanding loads. Split each chain across 4 lanes (q = edge idx mod
// 4): 6250 blocks = thread-slot-saturated 32 waves/CU, 4x aggregate MLP.
// Merge (m, den, A[12]) with 2-round shfl_xor butterfly; each q-lane writes 3
// of the 12 outputs.
__global__ __launch_bounds__(256) void gat_agg(const float* __restrict__ fs,
                                               const float* __restrict__ fd,
                                               const float* __restrict__ attn,
                                               const int* __restrict__ row_start,
                                               const int* __restrict__ csr_src,
                                               const int* __restrict__ perm,
                                               float* __restrict__ hout, int N) {
    int tid = blockIdx.x * 256 + threadIdx.x;
    int p = tid >> 5;           // node (perm index)
    int hd = (tid >> 2) & 7;    // head
    int q = tid & 3;            // edge quarter
    if (p >= N) return;
    int n = perm[p];
    float att[12], fdv[12];
    {
        const float4* ap = (const float4*)(attn + hd * 12);
        float4 a0 = ap[0], a1 = ap[1], a2 = ap[2];
        att[0]=a0.x; att[1]=a0.y; att[2]=a0.z; att[3]=a0.w;
        att[4]=a1.x; att[5]=a1.y; att[6]=a1.z; att[7]=a1.w;
        att[8]=a2.x; att[9]=a2.y; att[10]=a2.z; att[11]=a2.w;
        const float4* dp = (const float4*)(fd + (size_t)n * 96 + hd * 12);
        float4 d0 = dp[0], d1 = dp[1], d2 = dp[2];
        fdv[0]=d0.x; fdv[1]=d0.y; fdv[2]=d0.z; fdv[3]=d0.w;
        fdv[4]=d1.x; fdv[5]=d1.y; fdv[6]=d1.z; fdv[7]=d1.w;
        fdv[8]=d2.x; fdv[9]=d2.y; fdv[10]=d2.z; fdv[11]=d2.w;
    }
    int beg = row_start[n], end = row_start[n + 1];
    float m = -3.0e38f, den = 0.f;
    float A[12];
#pragma unroll
    for (int d = 0; d < 12; ++d) A[d] = 0.f;

    for (int e = beg + q; e < end; e += 4) {
        int i0 = csr_src[e];
        const float4* p0 = (const float4*)(fs + (size_t)i0 * 96 + hd * 12);
        float4 s0 = p0[0], s1 = p0[1], s2 = p0[2];
        float fsv[12];
        fsv[0]=s0.x; fsv[1]=s0.y; fsv[2]=s0.z; fsv[3]=s0.w;
        fsv[4]=s1.x; fsv[5]=s1.y; fsv[6]=s1.z; fsv[7]=s1.w;
        fsv[8]=s2.x; fsv[9]=s2.y; fsv[10]=s2.z; fsv[11]=s2.w;
        float logit = 0.f;
#pragma unroll
        for (int d = 0; d < 12; ++d) {
            float u = fsv[d] + fdv[d];
            u = u > 0.f ? u : 0.2f * u;
            logit = fmaf(u, att[d], logit);
        }
        float nm = fmaxf(m, logit);
        float cc = __expf(m - nm);
        float w  = __expf(logit - nm);
        den = fmaf(den, cc, w);
#pragma unroll
        for (int d = 0; d < 12; ++d) A[d] = fmaf(A[d], cc, w * fsv[d]);
        m = nm;
    }

    // butterfly merge across the 4 q-lanes (all lanes end with the full state)
#pragma unroll
    for (int off = 1; off <= 2; off <<= 1) {
        float m2   = __shfl_xor(m, off, 64);
        float den2 = __shfl_xor(den, off, 64);
        float nm = fmaxf(m, m2);
        float c1 = __expf(m - nm);
        float c2 = __expf(m2 - nm);
        den = den * c1 + den2 * c2;
#pragma unroll
        for (int d = 0; d < 12; ++d) {
            float a2 = __shfl_xor(A[d], off, 64);
            A[d] = A[d] * c1 + a2 * c2;
        }
        m = nm;
    }

    float inv = den > 0.f ? 1.f / den : 0.f;
    float* op = hout + (size_t)n * 96 + hd * 12;
    // each q-lane writes 3 of the 12 outputs
#pragma unroll
    for (int j = 0; j < 3; ++j) {
        int d = q * 3 + j;
        float v = (d == 0) ? A[0] : (d == 1) ? A[1] : (d == 2) ? A[2] : (d == 3) ? A[3]
                : (d == 4) ? A[4] : (d == 5) ? A[5] : (d == 6) ? A[6] : (d == 7) ? A[7]
                : (d == 8) ? A[8] : (d == 9) ? A[9] : (d == 10) ? A[10] : A[11];
        op[d] = fmaxf(v * inv, 0.f);
    }
}

// ---------------- per-graph max readout: stage 1 ----------------
__global__ __launch_bounds__(384) void readout_partial(const float* __restrict__ h,
                                                       const int* __restrict__ graph_id,
                                                       float* __restrict__ partial, int N) {
    __shared__ int lhg[GG * 96];
    int t = threadIdx.x;
    for (int i = t; i < GG * 96; i += 384) lhg[i] = 0;
    __syncthreads();
    int f = t % 96, nl = t / 96;
    for (int n0 = blockIdx.x * 4; n0 < N; n0 += RB * 4) {
        int n = n0 + nl;
        if (n < N) {
            int g = graph_id[n];
            float v = h[(size_t)n * 96 + f];
            atomicMax(&lhg[g * 96 + f], __float_as_int(v));
        }
    }
    __syncthreads();
    for (int i = t; i < GG * 96; i += 384)
        partial[(size_t)blockIdx.x * (GG * 96) + i] = __int_as_float(lhg[i]);
}

// ---------------- readout stage 2: reduce partials ----------------
__global__ void readout_reduce(const float* __restrict__ partial, float* __restrict__ hg) {
    int i = blockIdx.x * 256 + threadIdx.x;
    if (i < GG * 96) {
        float m = 0.f;
        for (int b = 0; b < RB; ++b) m = fmaxf(m, partial[(size_t)b * (GG * 96) + i]);
        hg[i] = m;
    }
}

// ---------------- classifier MLP: one block per graph ----------------
__global__ __launch_bounds__(96) void mlp_kernel(const float* __restrict__ hg,
                                                 const float* __restrict__ Wc1, const float* __restrict__ bc1,
                                                 const float* __restrict__ Wc2, const float* __restrict__ bc2,
                                                 const float* __restrict__ Wc3, const float* __restrict__ bc3,
                                                 float* __restrict__ out) {
    int g = blockIdx.x;
    int t = threadIdx.x;
    __shared__ float z0[96], z1[96], z2[48];
    z0[t] = hg[(size_t)g * 96 + t];
    __syncthreads();
    float s = bc1[t];
    for (int k = 0; k < 96; ++k) s = fmaf(z0[k], Wc1[k * 96 + t], s);
    z1[t] = fmaxf(s, 0.f);
    __syncthreads();
    if (t < 48) {
        float s2 = bc2[t];
        for (int k = 0; k < 96; ++k) s2 = fmaf(z1[k], Wc2[k * 48 + t], s2);
        z2[t] = fmaxf(s2, 0.f);
    }
    __syncthreads();
    if (t < 10) {
        float s3 = bc3[t];
        for (int k = 0; k < 48; ++k) s3 = fmaf(z2[k], Wc3[k * 10 + t], s3);
        out[(size_t)g * 10 + t] = s3;
    }
}

extern "C" void kernel_launch(void* const* d_in, const int* in_sizes, int n_in,
                              void* d_out, int out_size, void* d_ws, size_t ws_size,
                              hipStream_t stream) {
    const float* x        = (const float*)d_in[0];
    const int*   src      = (const int*)d_in[1];
    const int*   dst      = (const int*)d_in[2];
    const int*   graph_id = (const int*)d_in[3];
    const float* W1  = (const float*)d_in[4];
    const float* b1  = (const float*)d_in[5];
    const float* W2  = (const float*)d_in[6];
    const float* b2  = (const float*)d_in[7];
    const float* Ws  = (const float*)d_in[8];
    const float* bs  = (const float*)d_in[9];
    const float* Wd  = (const float*)d_in[10];
    const float* bd  = (const float*)d_in[11];
    const float* attn = (const float*)d_in[12];
    const float* Wc1 = (const float*)d_in[13];
    const float* bc1 = (const float*)d_in[14];
    const float* Wc2 = (const float*)d_in[15];
    const float* bc2 = (const float*)d_in[16];
    const float* Wc3 = (const float*)d_in[17];
    const float* bc3 = (const float*)d_in[18];
    float* out = (float*)d_out;

    char* ws = (char*)d_ws;
    size_t off = 0;
    auto alloc = [&](size_t bytes) {
        char* p = ws + off;
        off = (off + bytes + 255) & ~(size_t)255;
        return p;
    };
    int*   cnt_in    = (int*)alloc(Nn * 4);
    int*   row_start = (int*)alloc((Nn + 1) * 4);
    unsigned char* edge_slot = (unsigned char*)alloc(Ee);
    int*   csr_src   = (int*)alloc(Ee * 4);
    int*   perm      = (int*)alloc(Nn * 4);
    float* degI_is   = (float*)alloc(Nn * 4);
    float* degO_is   = (float*)alloc(Nn * 4);
    float* bufH      = (float*)alloc((size_t)Nn * 96 * 4);
    float* bufT      = (float*)alloc((size_t)Nn * 96 * 4);
    float* bufFd     = (float*)alloc((size_t)Nn * 96 * 4);
    float* hg        = (float*)alloc(GG * 96 * 4);
    float* partial   = (float*)alloc((size_t)RB * GG * 96 * 4);
    int*   blk_sum   = (int*)alloc(128 * 4);
    int*   blk_off   = (int*)alloc(128 * 4);
    int*   dcnt      = (int*)alloc(DBIN * 4);
    int*   dcur      = (int*)alloc(DBIN * 4);

    // packed histogram partials alias the (not-yet-used) feature buffers:
    // HCHK*NW*4 = 12.8 MB each; bufT/bufFd are 19.2 MB each.
    unsigned int* partS = (unsigned int*)bufT;
    unsigned int* partD = (unsigned int*)bufFd;

    hipMemsetAsync(dcnt, 0, DBIN * 4, stream);

    // ---- CSR build + degrees + degree-sort (no global fp atomics, 6 kernels) ----
    hist_lds<<<HCHK, 512, 0, stream>>>(src, dst, partS, partD, edge_slot);
    hist_scan<<<(NW + 255) / 256, 256, 0, stream>>>(partD, partS, cnt_in, degI_is, degO_is, dcnt);
    scan1_kernel<<<SCAN_BLOCKS, 256, 0, stream>>>(cnt_in, row_start, blk_sum, Nn);
    scan2_kernel<<<2, 128, 0, stream>>>(blk_sum, blk_off, row_start, dcnt, dcur, Nn);
    scan3_kernel<<<SCAN_BLOCKS + NSB, 256, 0, stream>>>(row_start, blk_off, cnt_in, dcur, perm, Nn);
    fill_kernel<<<HCHK, 512, 0, stream>>>(src, dst, row_start, partD, edge_slot, csr_src);

    int gemm_blocks = (Nn + 63) / 64;
    int agg_blocks  = (Nn * 24 + 191) / 192;
    int gat_blocks  = (Nn * 32 + 255) / 256;   // 4-way edge-split: 32 threads/node

    // GraphConv 1: x[N,128] -> bufH
    gemm96<<<gemm_blocks, 192, 0, stream>>>(x, 128, W1, nullptr, degO_is, bufT, Nn);
    gc_agg<<<agg_blocks, 192, 0, stream>>>(bufT, row_start, csr_src, degI_is, b1, perm, bufH, Nn);
    // GraphConv 2
    gemm96<<<gemm_blocks, 192, 0, stream>>>(bufH, 96, W2, nullptr, degO_is, bufT, Nn);
    gc_agg<<<agg_blocks, 192, 0, stream>>>(bufT, row_start, csr_src, degI_is, b2, perm, bufH, Nn);

    // 3x GATv2: fused dual GEMM (fs,fd) then fused attention+aggregate
    for (int l = 0; l < 3; ++l) {
        const float* Wsl = Ws + (size_t)l * 96 * 96;
        const float* bsl = bs + (size_t)l * 96;
        const float* Wdl = Wd + (size_t)l * 96 * 96;
        const float* bdl = bd + (size_t)l * 96;
        const float* atl = attn + (size_t)l * 96;
        gemm96x2<<<gemm_blocks, 192, 0, stream>>>(bufH, Wsl, bsl, Wdl, bdl, bufT, bufFd, Nn);
        gat_agg<<<gat_blocks, 256, 0, stream>>>(bufT, bufFd, atl, row_start, csr_src, perm, bufH, Nn);
    }

    readout_partial<<<RB, 384, 0, stream>>>(bufH, graph_id, partial, Nn);
    readout_reduce<<<(GG * 96 + 255) / 256, 256, 0, stream>>>(partial, hg);
    mlp_kernel<<<GG, 96, 0, stream>>>(hg, Wc1, bc1, Wc2, bc2, Wc3, bc3, out);
}